// Round 14
// baseline (99.241 us; speedup 1.0000x reference)
//
#include <hip/hip_runtime.h>
#include <hip/hip_bf16.h>

#define N_NODES 100000
#define N_EDGES 1600000
#define D_IN    128
#define D_HID   16
#define D_OUT   32

#define BSHIFT 8
#define BNODES 256                 // nodes per bucket
#define NB 391                     // ceil(100000/256)
#define NBPAD 512
#define SCHUNK 4096                // edges per sort block
#define SBLOCKS 391                // ceil(1600000/4096)
#define MMBLOCKS 782               // mm1: 2 nodes/thread, 4 lanes/node
#define SLAB 4608                  // slab slots per bucket (mean 4096, +8 sigma)
#define NOSTRIDE 257               // node_off stride per bucket (256 + sentinel)

// bf16x2 helpers -------------------------------------------------------------
__device__ inline float bf_lo(unsigned dw) { return __uint_as_float(dw << 16); }
__device__ inline float bf_hi(unsigned dw) { return __uint_as_float(dw & 0xffff0000u); }
__device__ inline unsigned bf_pack(float f0, float f1) {
    union { __hip_bfloat16 h[2]; unsigned u; } pu;
    pu.h[0] = __float2bfloat16(f0);
    pu.h[1] = __float2bfloat16(f1);
    return pu.u;
}
__device__ inline void acc4(float* a, uint2 w) {
    a[0] += bf_lo(w.x); a[1] += bf_hi(w.x);
    a[2] += bf_lo(w.y); a[3] += bf_hi(w.y);
}

// ---------------------------------------------------------------------------
// K1: Y = feat @ W1 -> packed bf16. 2 nodes/thread, 4 jq lanes/node: halves
// the LDS W-read count (the kernel's bottleneck) vs 1 node/thread. 8 KB LDS,
// 782 blocks -> full occupancy. Also initializes slab cursors (race-free:
// sortscatter is a later kernel on the same stream).
// ---------------------------------------------------------------------------
__global__ __launch_bounds__(256) void k_mm1(const float* __restrict__ feat,
                                             const float* __restrict__ W1,
                                             unsigned* __restrict__ Yu,
                                             int* __restrict__ cursor) {
    __shared__ float sW[D_IN * D_HID];  // 8 KB
    int tid = threadIdx.x, blk = blockIdx.x;
    for (int i = tid; i < D_IN * D_HID; i += 256) sW[i] = W1[i];
    if (tid == 0 && blk < NB) cursor[blk] = blk * SLAB;
    __syncthreads();

    int gid = blk * 256 + tid;
    int p = gid >> 2;          // node pair
    int jq = gid & 3;          // output quad
    int n0 = p * 2, n1 = p * 2 + 1;
    if (n0 >= N_NODES) return;
    bool has1 = (n1 < N_NODES);

    const float4* f40 = (const float4*)(feat + (size_t)n0 * D_IN);
    const float4* f41 = (const float4*)(feat + (size_t)n1 * D_IN);
    const float4* sW4 = (const float4*)sW;

    float4 acc0 = make_float4(0.f, 0.f, 0.f, 0.f);
    float4 acc1 = make_float4(0.f, 0.f, 0.f, 0.f);
#pragma unroll 4
    for (int kq = 0; kq < 32; ++kq) {
        float4 f0 = f40[kq];
        float4 f1 = has1 ? f41[kq] : make_float4(0.f, 0.f, 0.f, 0.f);
        int k0 = kq * 4;
        float4 w0 = sW4[(k0 + 0) * 4 + jq];
        float4 w1 = sW4[(k0 + 1) * 4 + jq];
        float4 w2 = sW4[(k0 + 2) * 4 + jq];
        float4 w3 = sW4[(k0 + 3) * 4 + jq];
        acc0.x += f0.x * w0.x + f0.y * w1.x + f0.z * w2.x + f0.w * w3.x;
        acc0.y += f0.x * w0.y + f0.y * w1.y + f0.z * w2.y + f0.w * w3.y;
        acc0.z += f0.x * w0.z + f0.y * w1.z + f0.z * w2.z + f0.w * w3.z;
        acc0.w += f0.x * w0.w + f0.y * w1.w + f0.z * w2.w + f0.w * w3.w;
        acc1.x += f1.x * w0.x + f1.y * w1.x + f1.z * w2.x + f1.w * w3.x;
        acc1.y += f1.x * w0.y + f1.y * w1.y + f1.z * w2.y + f1.w * w3.y;
        acc1.z += f1.x * w0.z + f1.y * w1.z + f1.z * w2.z + f1.w * w3.z;
        acc1.w += f1.x * w0.w + f1.y * w1.w + f1.z * w2.w + f1.w * w3.w;
    }
    uint2 o0;
    o0.x = bf_pack(acc0.x, acc0.y);
    o0.y = bf_pack(acc0.z, acc0.w);
    ((uint2*)(Yu + (size_t)n0 * 8))[jq] = o0;
    if (has1) {
        uint2 o1;
        o1.x = bf_pack(acc1.x, acc1.y);
        o1.y = bf_pack(acc1.z, acc1.w);
        ((uint2*)(Yu + (size_t)n1 * 8))[jq] = o1;
    }
}

// ---------------------------------------------------------------------------
// K2: block-local counting sort + run-reserved slab writeout (round 11 code).
// ~10.5-edge runs -> mostly-contiguous global writes.
// pairs value = (src << 8) | (dst & 255).
// ---------------------------------------------------------------------------
__global__ __launch_bounds__(256) void k_sortscatter(const int* __restrict__ src,
                                                     const int* __restrict__ dst,
                                                     int* __restrict__ cursor,
                                                     unsigned* __restrict__ pairs) {
    __shared__ int hist[NBPAD];         // 2 KB, reused as placement counters
    __shared__ int lbase[NBPAD];        // 2 KB
    __shared__ int gbase[NB];           // 1.6 KB
    __shared__ int tscan[256];          // 1 KB
    __shared__ unsigned sorted[SCHUNK]; // 16 KB
    __shared__ unsigned short bId[SCHUNK]; // 8 KB

    int tid = threadIdx.x;
    int base = blockIdx.x * SCHUNK;
    int nval = N_EDGES - base;
    if (nval > SCHUNK) nval = SCHUNK;

    for (int i = tid; i < NBPAD; i += 256) hist[i] = 0;
    __syncthreads();

    int varr[16], barr[16];
#pragma unroll
    for (int k = 0; k < 16; ++k) {
        int e = base + k * 256 + tid;
        if (e < N_EDGES) {
            int s = src[e], d = dst[e];
            varr[k] = (s << BSHIFT) | (d & (BNODES - 1));
            int b = d >> BSHIFT;
            barr[k] = b;
            atomicAdd(&hist[b], 1);
        } else {
            barr[k] = -1;
        }
    }
    __syncthreads();

    int i0 = tid * 2;
    int h0 = hist[i0], h1 = hist[i0 + 1];
    int lsum = h0 + h1;
    tscan[tid] = lsum;
    __syncthreads();
#pragma unroll
    for (int off = 1; off < 256; off <<= 1) {
        int x = (tid >= off) ? tscan[tid - off] : 0;
        __syncthreads();
        tscan[tid] += x;
        __syncthreads();
    }
    int excl = tscan[tid] - lsum;
    lbase[i0 + 0] = excl;
    lbase[i0 + 1] = excl + h0;
    __syncthreads();

    for (int i = tid; i < NB; i += 256) {
        int c = hist[i];
        if (c > 0) gbase[i] = atomicAdd(&cursor[i], c);
    }
    __syncthreads();
    for (int i = tid; i < NBPAD; i += 256) hist[i] = 0;   // -> placement cnt
    __syncthreads();

#pragma unroll
    for (int k = 0; k < 16; ++k) {
        int b = barr[k];
        if (b >= 0) {
            int r = atomicAdd(&hist[b], 1);
            int p = lbase[b] + r;
            sorted[p] = (unsigned)varr[k];
            bId[p] = (unsigned short)b;
        }
    }
    __syncthreads();

    for (int i = tid; i < nval; i += 256) {
        int b = bId[i];
        pairs[gbase[b] + (i - lbase[b])] = sorted[i];
    }
}

// ---------------------------------------------------------------------------
// K3: per-bucket node sort (256 keys, 1 thread per key). In-place rewrite of
// pairs -> node-sorted plain src ids + node_off (stride-257 layout).
// ---------------------------------------------------------------------------
__global__ __launch_bounds__(256) void k_nodesort(const int* __restrict__ cursor,
                                                  unsigned* __restrict__ pairs,
                                                  int* __restrict__ node_off) {
    __shared__ unsigned buf[SLAB];      // 18 KB
    __shared__ int hist[BNODES];
    __shared__ int cur[BNODES];
    __shared__ int t[256];

    int tid = threadIdx.x, b = blockIdx.x;
    int beg = b * SLAB;
    int cnt = cursor[b] - beg;

    hist[tid] = 0;
    __syncthreads();

    for (int i = tid; i < cnt; i += 256) {
        unsigned p = pairs[beg + i];
        buf[i] = p;
        atomicAdd(&hist[p & (BNODES - 1)], 1);
    }
    __syncthreads();

    int v = hist[tid];
    t[tid] = v;
    __syncthreads();
#pragma unroll
    for (int off = 1; off < 256; off <<= 1) {
        int x = (tid >= off) ? t[tid - off] : 0;
        __syncthreads();
        t[tid] += x;
        __syncthreads();
    }
    int excl = t[tid] - v;
    cur[tid] = excl;
    node_off[b * NOSTRIDE + tid] = beg + excl;
    if (tid == 0) node_off[b * NOSTRIDE + BNODES] = beg + cnt;  // sentinel
    __syncthreads();

    for (int i = tid; i < cnt; i += 256) {
        unsigned p = buf[i];
        int pos = atomicAdd(&cur[p & (BNODES - 1)], 1);
        pairs[beg + pos] = p >> BSHIFT;    // plain src id, node-sorted
    }
}

// ---------------------------------------------------------------------------
// K4: layer-1 aggregation (round 11 code): 64 nodes/block, 4 lanes/node,
// uint2 (8B) gathers, simple 8-deep unroll. Register accumulation, fused
// bias+ReLU -> packed bf16 H1.
// ---------------------------------------------------------------------------
__global__ __launch_bounds__(256) void k_agg1(const int* __restrict__ node_off,
                                              const unsigned* __restrict__ csr,
                                              const uint2* __restrict__ Yu2,
                                              const float* __restrict__ bias1,
                                              uint2* __restrict__ H1u2) {
    int tid = threadIdx.x;
    int g = tid >> 2, c = tid & 3;
    int n = blockIdx.x * 64 + g;
    if (n >= N_NODES) return;
    int idx = n + (n >> 8);
    int beg = node_off[idx], end = node_off[idx + 1];

    float a[4] = {0.f, 0.f, 0.f, 0.f}, b[4] = {0.f, 0.f, 0.f, 0.f};
    int i = beg;
    for (; i + 7 < end; i += 8) {
        unsigned s0 = csr[i],     s1 = csr[i + 1], s2 = csr[i + 2], s3 = csr[i + 3];
        unsigned s4 = csr[i + 4], s5 = csr[i + 5], s6 = csr[i + 6], s7 = csr[i + 7];
        uint2 w0 = Yu2[(size_t)s0 * 4 + c];
        uint2 w1 = Yu2[(size_t)s1 * 4 + c];
        uint2 w2 = Yu2[(size_t)s2 * 4 + c];
        uint2 w3 = Yu2[(size_t)s3 * 4 + c];
        uint2 w4 = Yu2[(size_t)s4 * 4 + c];
        uint2 w5 = Yu2[(size_t)s5 * 4 + c];
        uint2 w6 = Yu2[(size_t)s6 * 4 + c];
        uint2 w7 = Yu2[(size_t)s7 * 4 + c];
        acc4(a, w0); acc4(b, w1); acc4(a, w2); acc4(b, w3);
        acc4(a, w4); acc4(b, w5); acc4(a, w6); acc4(b, w7);
    }
    for (; i < end; ++i) {
        uint2 w = Yu2[(size_t)csr[i] * 4 + c];
        acc4(a, w);
    }
    float f0 = a[0] + b[0] + bias1[c * 4 + 0];
    float f1 = a[1] + b[1] + bias1[c * 4 + 1];
    float f2 = a[2] + b[2] + bias1[c * 4 + 2];
    float f3 = a[3] + b[3] + bias1[c * 4 + 3];
    uint2 o;
    o.x = bf_pack(fmaxf(f0, 0.f), fmaxf(f1, 0.f));
    o.y = bf_pack(fmaxf(f2, 0.f), fmaxf(f3, 0.f));
    H1u2[(size_t)n * 4 + c] = o;
}

// ---------------------------------------------------------------------------
// K5: layer-2 aggregation (round 11 code) + fused mm2 epilogue.
// ---------------------------------------------------------------------------
__global__ __launch_bounds__(256) void k_agg2(const int* __restrict__ node_off,
                                              const unsigned* __restrict__ csr,
                                              const uint2* __restrict__ H1u2,
                                              const float* __restrict__ W2,
                                              const float* __restrict__ b2,
                                              float* __restrict__ out) {
    __shared__ float sacc[64][D_HID + 1];  // 4.4 KB
    __shared__ float sW2[D_HID * D_OUT];   // 2 KB
    __shared__ float sb2[D_OUT];
    int tid = threadIdx.x;
    for (int i2 = tid; i2 < D_HID * D_OUT; i2 += 256) sW2[i2] = W2[i2];
    if (tid < D_OUT) sb2[tid] = b2[tid];

    int g = tid >> 2, c = tid & 3;
    int n = blockIdx.x * 64 + g;

    float a[4] = {0.f, 0.f, 0.f, 0.f}, b[4] = {0.f, 0.f, 0.f, 0.f};
    if (n < N_NODES) {
        int idx = n + (n >> 8);
        int beg = node_off[idx], end = node_off[idx + 1];
        int i = beg;
        for (; i + 7 < end; i += 8) {
            unsigned s0 = csr[i],     s1 = csr[i + 1], s2 = csr[i + 2], s3 = csr[i + 3];
            unsigned s4 = csr[i + 4], s5 = csr[i + 5], s6 = csr[i + 6], s7 = csr[i + 7];
            uint2 w0 = H1u2[(size_t)s0 * 4 + c];
            uint2 w1 = H1u2[(size_t)s1 * 4 + c];
            uint2 w2 = H1u2[(size_t)s2 * 4 + c];
            uint2 w3 = H1u2[(size_t)s3 * 4 + c];
            uint2 w4 = H1u2[(size_t)s4 * 4 + c];
            uint2 w5 = H1u2[(size_t)s5 * 4 + c];
            uint2 w6 = H1u2[(size_t)s6 * 4 + c];
            uint2 w7 = H1u2[(size_t)s7 * 4 + c];
            acc4(a, w0); acc4(b, w1); acc4(a, w2); acc4(b, w3);
            acc4(a, w4); acc4(b, w5); acc4(a, w6); acc4(b, w7);
        }
        for (; i < end; ++i) {
            uint2 w = H1u2[(size_t)csr[i] * 4 + c];
            acc4(a, w);
        }
    }
    sacc[g][c * 4 + 0] = a[0] + b[0];
    sacc[g][c * 4 + 1] = a[1] + b[1];
    sacc[g][c * 4 + 2] = a[2] + b[2];
    sacc[g][c * 4 + 3] = a[3] + b[3];
    __syncthreads();

    // mm2: 64 nodes x 32 outputs = 2048 -> 8 per thread
    for (int t2 = tid; t2 < 64 * D_OUT; t2 += 256) {
        int gg = t2 >> 5, o = t2 & 31;
        int node = blockIdx.x * 64 + gg;
        if (node < N_NODES) {
            float acc = sb2[o];
#pragma unroll
            for (int j = 0; j < D_HID; ++j)
                acc = fmaf(sacc[gg][j], sW2[j * D_OUT + o], acc);
            out[(size_t)node * D_OUT + o] = acc;
        }
    }
}

// ---------------------------------------------------------------------------
extern "C" void kernel_launch(void* const* d_in, const int* in_sizes, int n_in,
                              void* d_out, int out_size, void* d_ws, size_t ws_size,
                              hipStream_t stream) {
    const float* feat = (const float*)d_in[0];
    const int*   src  = (const int*)d_in[1];
    const int*   dst  = (const int*)d_in[2];
    const float* W1   = (const float*)d_in[3];
    const float* b1   = (const float*)d_in[4];
    const float* W2   = (const float*)d_in[5];
    const float* b2   = (const float*)d_in[6];
    float* out = (float*)d_out;

    // ws layout (~14.0 MB):
    //   [0        , 7206912 )  pairs/csr slabs (NB * SLAB u32)
    //   [7208960  , +3.2M   )  Yu   (bf16x16 rows, packed, 16B aligned)
    //   [10408960 , +3.2M   )  H1u  (bf16x16 rows, packed, 16B aligned)
    //   [13608960 , +1.6K   )  cursor   (NB ints, slab-based)
    //   [13613056 , +402K   )  node_off (NB*257 ints)
    char* base = (char*)d_ws;
    unsigned* pairs    = (unsigned*)(base);
    unsigned* Yu       = (unsigned*)(base + 7208960);
    unsigned* H1u      = (unsigned*)(base + 10408960);
    int*      cursor   = (int*)(base + 13608960);
    int*      node_off = (int*)(base + 13613056);

    // K1: projection (2 nodes/thread) + slab cursor init
    k_mm1        <<<MMBLOCKS, 256, 0, stream>>>(feat, W1, Yu, cursor);
    // K2: bucket-grouping counting sort into slabs
    k_sortscatter<<<SBLOCKS, 256, 0, stream>>>(src, dst, cursor, pairs);
    // K3: per-bucket node sort -> csr + node_off
    k_nodesort   <<<NB, 256, 0, stream>>>(cursor, pairs, node_off);
    // K4: layer-1 aggregation (fused bias+ReLU)
    k_agg1       <<<(N_NODES + 63) / 64, 256, 0, stream>>>(node_off, pairs,
                                                           (const uint2*)Yu, b1,
                                                           (uint2*)H1u);
    // K5: layer-2 aggregation + fused mm2
    k_agg2       <<<(N_NODES + 63) / 64, 256, 0, stream>>>(node_off, pairs,
                                                           (const uint2*)H1u, W2, b2, out);
}

// Round 15
// 91.502 us; speedup vs baseline: 1.0846x; 1.0846x over previous
//
#include <hip/hip_runtime.h>
#include <hip/hip_bf16.h>

#define N_NODES 100000
#define N_EDGES 1600000
#define D_IN    128
#define D_HID   16
#define D_OUT   32

#define BSHIFT 8
#define BNODES 256                 // nodes per bucket
#define NB 391                     // ceil(100000/256)
#define NBPAD 512
#define SCHUNK 4096                // edges per sort block
#define SBLOCKS 391                // ceil(1600000/4096)
#define SLAB 4608                  // slab slots per bucket (mean 4096, +8 sigma)
#define NOSTRIDE 257               // node_off stride per bucket (256 + sentinel)

// bf16x2 helpers -------------------------------------------------------------
__device__ inline float bf_lo(unsigned dw) { return __uint_as_float(dw << 16); }
__device__ inline float bf_hi(unsigned dw) { return __uint_as_float(dw & 0xffff0000u); }
__device__ inline unsigned bf_pack(float f0, float f1) {
    union { __hip_bfloat16 h[2]; unsigned u; } pu;
    pu.h[0] = __float2bfloat16(f0);
    pu.h[1] = __float2bfloat16(f1);
    return pu.u;
}
__device__ inline void acc4(float* a, uint2 w) {
    a[0] += bf_lo(w.x); a[1] += bf_hi(w.x);
    a[2] += bf_lo(w.y); a[3] += bf_hi(w.y);
}

// ---------------------------------------------------------------------------
// K1: Y = feat @ W1 -> packed bf16. 1 node/thread-quad (4 jq lanes/node),
// 400K threads / 1563 blocks: mm1 is feat-load-latency-bound, so maximize
// wave count (round 14 lesson: 2 nodes/thread halved waves and cost +8us).
// Also initializes slab cursors (race-free: sortscatter is 2 kernels later).
// ---------------------------------------------------------------------------
__global__ __launch_bounds__(256) void k_mm1(const float* __restrict__ feat,
                                             const float* __restrict__ W1,
                                             unsigned* __restrict__ Yu,
                                             int* __restrict__ cursor) {
    __shared__ float sW[D_IN * D_HID];  // 8 KB
    int tid = threadIdx.x, blk = blockIdx.x;
    for (int i = tid; i < D_IN * D_HID; i += 256) sW[i] = W1[i];
    if (tid == 0 && blk < NB) cursor[blk] = blk * SLAB;
    __syncthreads();

    int gid = blk * 256 + tid;
    int n = gid >> 2;          // node
    int jq = gid & 3;          // output quad
    if (n >= N_NODES) return;

    const float4* f4 = (const float4*)(feat + (size_t)n * D_IN);
    const float4* sW4 = (const float4*)sW;

    float4 acc = make_float4(0.f, 0.f, 0.f, 0.f);
#pragma unroll 8
    for (int kq = 0; kq < 32; ++kq) {
        float4 f = f4[kq];
        int k0 = kq * 4;
        float4 w0 = sW4[(k0 + 0) * 4 + jq];
        float4 w1 = sW4[(k0 + 1) * 4 + jq];
        float4 w2 = sW4[(k0 + 2) * 4 + jq];
        float4 w3 = sW4[(k0 + 3) * 4 + jq];
        acc.x += f.x * w0.x + f.y * w1.x + f.z * w2.x + f.w * w3.x;
        acc.y += f.x * w0.y + f.y * w1.y + f.z * w2.y + f.w * w3.y;
        acc.z += f.x * w0.z + f.y * w1.z + f.z * w2.z + f.w * w3.z;
        acc.w += f.x * w0.w + f.y * w1.w + f.z * w2.w + f.w * w3.w;
    }
    uint2 o;
    o.x = bf_pack(acc.x, acc.y);
    o.y = bf_pack(acc.z, acc.w);
    ((uint2*)(Yu + (size_t)n * 8))[jq] = o;
}

// ---------------------------------------------------------------------------
// K2: block-local counting sort + run-reserved slab writeout. ~10.5-edge runs
// -> mostly-contiguous global writes. pairs value = (src << 8) | (dst & 255).
// ---------------------------------------------------------------------------
__global__ __launch_bounds__(256) void k_sortscatter(const int* __restrict__ src,
                                                     const int* __restrict__ dst,
                                                     int* __restrict__ cursor,
                                                     unsigned* __restrict__ pairs) {
    __shared__ int hist[NBPAD];         // 2 KB, reused as placement counters
    __shared__ int lbase[NBPAD];        // 2 KB
    __shared__ int gbase[NB];           // 1.6 KB
    __shared__ int tscan[256];          // 1 KB
    __shared__ unsigned sorted[SCHUNK]; // 16 KB
    __shared__ unsigned short bId[SCHUNK]; // 8 KB

    int tid = threadIdx.x;
    int base = blockIdx.x * SCHUNK;
    int nval = N_EDGES - base;
    if (nval > SCHUNK) nval = SCHUNK;

    for (int i = tid; i < NBPAD; i += 256) hist[i] = 0;
    __syncthreads();

    int varr[16], barr[16];
#pragma unroll
    for (int k = 0; k < 16; ++k) {
        int e = base + k * 256 + tid;
        if (e < N_EDGES) {
            int s = src[e], d = dst[e];
            varr[k] = (s << BSHIFT) | (d & (BNODES - 1));
            int b = d >> BSHIFT;
            barr[k] = b;
            atomicAdd(&hist[b], 1);
        } else {
            barr[k] = -1;
        }
    }
    __syncthreads();

    int i0 = tid * 2;
    int h0 = hist[i0], h1 = hist[i0 + 1];
    int lsum = h0 + h1;
    tscan[tid] = lsum;
    __syncthreads();
#pragma unroll
    for (int off = 1; off < 256; off <<= 1) {
        int x = (tid >= off) ? tscan[tid - off] : 0;
        __syncthreads();
        tscan[tid] += x;
        __syncthreads();
    }
    int excl = tscan[tid] - lsum;
    lbase[i0 + 0] = excl;
    lbase[i0 + 1] = excl + h0;
    __syncthreads();

    for (int i = tid; i < NB; i += 256) {
        int c = hist[i];
        if (c > 0) gbase[i] = atomicAdd(&cursor[i], c);
    }
    __syncthreads();
    for (int i = tid; i < NBPAD; i += 256) hist[i] = 0;   // -> placement cnt
    __syncthreads();

#pragma unroll
    for (int k = 0; k < 16; ++k) {
        int b = barr[k];
        if (b >= 0) {
            int r = atomicAdd(&hist[b], 1);
            int p = lbase[b] + r;
            sorted[p] = (unsigned)varr[k];
            bId[p] = (unsigned short)b;
        }
    }
    __syncthreads();

    for (int i = tid; i < nval; i += 256) {
        int b = bId[i];
        pairs[gbase[b] + (i - lbase[b])] = sorted[i];
    }
}

// ---------------------------------------------------------------------------
// K3: per-bucket node sort (256 keys, 1 thread per key). In-place rewrite of
// pairs -> node-sorted plain src ids + node_off (stride-257 layout).
// ---------------------------------------------------------------------------
__global__ __launch_bounds__(256) void k_nodesort(const int* __restrict__ cursor,
                                                  unsigned* __restrict__ pairs,
                                                  int* __restrict__ node_off) {
    __shared__ unsigned buf[SLAB];      // 18 KB
    __shared__ int hist[BNODES];
    __shared__ int cur[BNODES];
    __shared__ int t[256];

    int tid = threadIdx.x, b = blockIdx.x;
    int beg = b * SLAB;
    int cnt = cursor[b] - beg;

    hist[tid] = 0;
    __syncthreads();

    for (int i = tid; i < cnt; i += 256) {
        unsigned p = pairs[beg + i];
        buf[i] = p;
        atomicAdd(&hist[p & (BNODES - 1)], 1);
    }
    __syncthreads();

    int v = hist[tid];
    t[tid] = v;
    __syncthreads();
#pragma unroll
    for (int off = 1; off < 256; off <<= 1) {
        int x = (tid >= off) ? t[tid - off] : 0;
        __syncthreads();
        t[tid] += x;
        __syncthreads();
    }
    int excl = t[tid] - v;
    cur[tid] = excl;
    node_off[b * NOSTRIDE + tid] = beg + excl;
    if (tid == 0) node_off[b * NOSTRIDE + BNODES] = beg + cnt;  // sentinel
    __syncthreads();

    for (int i = tid; i < cnt; i += 256) {
        unsigned p = buf[i];
        int pos = atomicAdd(&cur[p & (BNODES - 1)], 1);
        pairs[beg + pos] = p >> BSHIFT;    // plain src id, node-sorted
    }
}

// ---------------------------------------------------------------------------
// K4: layer-1 aggregation: 64 nodes/block, 4 lanes/node, uint2 (8B) gathers,
// simple 8-deep unroll (compiler-scheduled MLP). Register accumulation,
// fused bias+ReLU -> packed bf16 H1.
// ---------------------------------------------------------------------------
__global__ __launch_bounds__(256) void k_agg1(const int* __restrict__ node_off,
                                              const unsigned* __restrict__ csr,
                                              const uint2* __restrict__ Yu2,
                                              const float* __restrict__ bias1,
                                              uint2* __restrict__ H1u2) {
    int tid = threadIdx.x;
    int g = tid >> 2, c = tid & 3;
    int n = blockIdx.x * 64 + g;
    if (n >= N_NODES) return;
    int idx = n + (n >> 8);
    int beg = node_off[idx], end = node_off[idx + 1];

    float a[4] = {0.f, 0.f, 0.f, 0.f}, b[4] = {0.f, 0.f, 0.f, 0.f};
    int i = beg;
    for (; i + 7 < end; i += 8) {
        unsigned s0 = csr[i],     s1 = csr[i + 1], s2 = csr[i + 2], s3 = csr[i + 3];
        unsigned s4 = csr[i + 4], s5 = csr[i + 5], s6 = csr[i + 6], s7 = csr[i + 7];
        uint2 w0 = Yu2[(size_t)s0 * 4 + c];
        uint2 w1 = Yu2[(size_t)s1 * 4 + c];
        uint2 w2 = Yu2[(size_t)s2 * 4 + c];
        uint2 w3 = Yu2[(size_t)s3 * 4 + c];
        uint2 w4 = Yu2[(size_t)s4 * 4 + c];
        uint2 w5 = Yu2[(size_t)s5 * 4 + c];
        uint2 w6 = Yu2[(size_t)s6 * 4 + c];
        uint2 w7 = Yu2[(size_t)s7 * 4 + c];
        acc4(a, w0); acc4(b, w1); acc4(a, w2); acc4(b, w3);
        acc4(a, w4); acc4(b, w5); acc4(a, w6); acc4(b, w7);
    }
    for (; i < end; ++i) {
        uint2 w = Yu2[(size_t)csr[i] * 4 + c];
        acc4(a, w);
    }
    float f0 = a[0] + b[0] + bias1[c * 4 + 0];
    float f1 = a[1] + b[1] + bias1[c * 4 + 1];
    float f2 = a[2] + b[2] + bias1[c * 4 + 2];
    float f3 = a[3] + b[3] + bias1[c * 4 + 3];
    uint2 o;
    o.x = bf_pack(fmaxf(f0, 0.f), fmaxf(f1, 0.f));
    o.y = bf_pack(fmaxf(f2, 0.f), fmaxf(f3, 0.f));
    H1u2[(size_t)n * 4 + c] = o;
}

// ---------------------------------------------------------------------------
// K5: layer-2 aggregation (same gather structure) + fused mm2 epilogue.
// ---------------------------------------------------------------------------
__global__ __launch_bounds__(256) void k_agg2(const int* __restrict__ node_off,
                                              const unsigned* __restrict__ csr,
                                              const uint2* __restrict__ H1u2,
                                              const float* __restrict__ W2,
                                              const float* __restrict__ b2,
                                              float* __restrict__ out) {
    __shared__ float sacc[64][D_HID + 1];  // 4.4 KB
    __shared__ float sW2[D_HID * D_OUT];   // 2 KB
    __shared__ float sb2[D_OUT];
    int tid = threadIdx.x;
    for (int i2 = tid; i2 < D_HID * D_OUT; i2 += 256) sW2[i2] = W2[i2];
    if (tid < D_OUT) sb2[tid] = b2[tid];

    int g = tid >> 2, c = tid & 3;
    int n = blockIdx.x * 64 + g;

    float a[4] = {0.f, 0.f, 0.f, 0.f}, b[4] = {0.f, 0.f, 0.f, 0.f};
    if (n < N_NODES) {
        int idx = n + (n >> 8);
        int beg = node_off[idx], end = node_off[idx + 1];
        int i = beg;
        for (; i + 7 < end; i += 8) {
            unsigned s0 = csr[i],     s1 = csr[i + 1], s2 = csr[i + 2], s3 = csr[i + 3];
            unsigned s4 = csr[i + 4], s5 = csr[i + 5], s6 = csr[i + 6], s7 = csr[i + 7];
            uint2 w0 = H1u2[(size_t)s0 * 4 + c];
            uint2 w1 = H1u2[(size_t)s1 * 4 + c];
            uint2 w2 = H1u2[(size_t)s2 * 4 + c];
            uint2 w3 = H1u2[(size_t)s3 * 4 + c];
            uint2 w4 = H1u2[(size_t)s4 * 4 + c];
            uint2 w5 = H1u2[(size_t)s5 * 4 + c];
            uint2 w6 = H1u2[(size_t)s6 * 4 + c];
            uint2 w7 = H1u2[(size_t)s7 * 4 + c];
            acc4(a, w0); acc4(b, w1); acc4(a, w2); acc4(b, w3);
            acc4(a, w4); acc4(b, w5); acc4(a, w6); acc4(b, w7);
        }
        for (; i < end; ++i) {
            uint2 w = H1u2[(size_t)csr[i] * 4 + c];
            acc4(a, w);
        }
    }
    sacc[g][c * 4 + 0] = a[0] + b[0];
    sacc[g][c * 4 + 1] = a[1] + b[1];
    sacc[g][c * 4 + 2] = a[2] + b[2];
    sacc[g][c * 4 + 3] = a[3] + b[3];
    __syncthreads();

    // mm2: 64 nodes x 32 outputs = 2048 -> 8 per thread
    for (int t2 = tid; t2 < 64 * D_OUT; t2 += 256) {
        int gg = t2 >> 5, o = t2 & 31;
        int node = blockIdx.x * 64 + gg;
        if (node < N_NODES) {
            float acc = sb2[o];
#pragma unroll
            for (int j = 0; j < D_HID; ++j)
                acc = fmaf(sacc[gg][j], sW2[j * D_OUT + o], acc);
            out[(size_t)node * D_OUT + o] = acc;
        }
    }
}

// ---------------------------------------------------------------------------
extern "C" void kernel_launch(void* const* d_in, const int* in_sizes, int n_in,
                              void* d_out, int out_size, void* d_ws, size_t ws_size,
                              hipStream_t stream) {
    const float* feat = (const float*)d_in[0];
    const int*   src  = (const int*)d_in[1];
    const int*   dst  = (const int*)d_in[2];
    const float* W1   = (const float*)d_in[3];
    const float* b1   = (const float*)d_in[4];
    const float* W2   = (const float*)d_in[5];
    const float* b2   = (const float*)d_in[6];
    float* out = (float*)d_out;

    // ws layout (~14.0 MB):
    //   [0        , 7206912 )  pairs/csr slabs (NB * SLAB u32)
    //   [7208960  , +3.2M   )  Yu   (bf16x16 rows, packed, 16B aligned)
    //   [10408960 , +3.2M   )  H1u  (bf16x16 rows, packed, 16B aligned)
    //   [13608960 , +1.6K   )  cursor   (NB ints, slab-based)
    //   [13613056 , +402K   )  node_off (NB*257 ints)
    char* base = (char*)d_ws;
    unsigned* pairs    = (unsigned*)(base);
    unsigned* Yu       = (unsigned*)(base + 7208960);
    unsigned* H1u      = (unsigned*)(base + 10408960);
    int*      cursor   = (int*)(base + 13608960);
    int*      node_off = (int*)(base + 13613056);

    // K1: projection (1 node/thread-quad, 1563 blocks) + slab cursor init
    k_mm1        <<<(N_NODES * 4 + 255) / 256, 256, 0, stream>>>(feat, W1, Yu, cursor);
    // K2: bucket-grouping counting sort into slabs
    k_sortscatter<<<SBLOCKS, 256, 0, stream>>>(src, dst, cursor, pairs);
    // K3: per-bucket node sort -> csr + node_off
    k_nodesort   <<<NB, 256, 0, stream>>>(cursor, pairs, node_off);
    // K4: layer-1 aggregation (fused bias+ReLU)
    k_agg1       <<<(N_NODES + 63) / 64, 256, 0, stream>>>(node_off, pairs,
                                                           (const uint2*)Yu, b1,
                                                           (uint2*)H1u);
    // K5: layer-2 aggregation + fused mm2
    k_agg2       <<<(N_NODES + 63) / 64, 256, 0, stream>>>(node_off, pairs,
                                                           (const uint2*)H1u, W2, b2, out);
}

// Round 16
// 89.726 us; speedup vs baseline: 1.1061x; 1.0198x over previous
//
#include <hip/hip_runtime.h>
#include <hip/hip_bf16.h>

#define N_NODES 100000
#define N_EDGES 1600000
#define D_IN    128
#define D_HID   16
#define D_OUT   32

#define BSHIFT 8
#define BNODES 256                 // nodes per bucket
#define NB 391                     // ceil(100000/256)
#define NBPAD 512
#define SCHUNK 4096                // edges per sort block
#define SBLOCKS 391                // ceil(1600000/4096)
#define MMBLOCKS 1563              // mm1: 1 node/thread-quad (proven round 11/15)
#define SLAB 4608                  // slab slots per bucket (mean 4096, +8 sigma)
#define NOSTRIDE 257               // node_off stride per bucket (256 + sentinel)

// shared-memory union layout for the fused kernel (bytes)
#define SS_HIST   0                // int[512]
#define SS_LBASE  2048             // int[512]
#define SS_GBASE  4096             // int[391] (pad to 1600)
#define SS_TSCAN  5696             // int[256]
#define SS_SORTED 6720             // unsigned[4096]
#define SS_BID    23104            // ushort[4096]
#define SS_BYTES  31296            // 31.3 KB -> 5 blocks/CU

// bf16x2 helpers -------------------------------------------------------------
__device__ inline float bf_lo(unsigned dw) { return __uint_as_float(dw << 16); }
__device__ inline float bf_hi(unsigned dw) { return __uint_as_float(dw & 0xffff0000u); }
__device__ inline unsigned bf_pack(float f0, float f1) {
    union { __hip_bfloat16 h[2]; unsigned u; } pu;
    pu.h[0] = __float2bfloat16(f0);
    pu.h[1] = __float2bfloat16(f1);
    return pu.u;
}
__device__ inline void acc4(float* a, uint2 w) {
    a[0] += bf_lo(w.x); a[1] += bf_hi(w.x);
    a[2] += bf_lo(w.y); a[3] += bf_hi(w.y);
}

// ---------------------------------------------------------------------------
// K1 (fused): blocks [0, SBLOCKS) = bucket-grouping counting sort (zero-based
// slab cursors); blocks [SBLOCKS, SBLOCKS+MMBLOCKS) = mm1 at 1 node/thread-
// quad (the proven latency-hiding config). The two halves read disjoint
// inputs with complementary bottlenecks and overlap on every CU.
// Validated by round differencing: fusion saved ~7-8us even when paired with
// a bad mm1 (r12=91.8 vs r14=99.2); here it pairs with the good mm1.
// ---------------------------------------------------------------------------
__global__ __launch_bounds__(256) void k_fused1(const float* __restrict__ feat,
                                                const float* __restrict__ W1,
                                                const int* __restrict__ src,
                                                const int* __restrict__ dst,
                                                int* __restrict__ cursor,
                                                unsigned* __restrict__ pairs,
                                                unsigned* __restrict__ Yu) {
    __shared__ __align__(16) char smem[SS_BYTES];
    int tid = threadIdx.x, blk = blockIdx.x;

    if (blk < SBLOCKS) {
        // ---------------- sortscatter path ----------------
        int* hist    = (int*)(smem + SS_HIST);
        int* lbase   = (int*)(smem + SS_LBASE);
        int* gbase   = (int*)(smem + SS_GBASE);
        int* tscan   = (int*)(smem + SS_TSCAN);
        unsigned* sorted = (unsigned*)(smem + SS_SORTED);
        unsigned short* bId = (unsigned short*)(smem + SS_BID);

        int base = blk * SCHUNK;
        int nval = N_EDGES - base;
        if (nval > SCHUNK) nval = SCHUNK;

        for (int i = tid; i < NBPAD; i += 256) hist[i] = 0;
        __syncthreads();

        int varr[16], barr[16];
#pragma unroll
        for (int k = 0; k < 16; ++k) {
            int e = base + k * 256 + tid;
            if (e < N_EDGES) {
                int s = src[e], d = dst[e];
                varr[k] = (s << BSHIFT) | (d & (BNODES - 1));
                int b = d >> BSHIFT;
                barr[k] = b;
                atomicAdd(&hist[b], 1);
            } else {
                barr[k] = -1;
            }
        }
        __syncthreads();

        // scan hist -> lbase (2 elems/thread, stride-2: conflict-free)
        int i0 = tid * 2;
        int h0 = hist[i0], h1 = hist[i0 + 1];
        int lsum = h0 + h1;
        tscan[tid] = lsum;
        __syncthreads();
#pragma unroll
        for (int off = 1; off < 256; off <<= 1) {
            int x = (tid >= off) ? tscan[tid - off] : 0;
            __syncthreads();
            tscan[tid] += x;
            __syncthreads();
        }
        int excl = tscan[tid] - lsum;
        lbase[i0 + 0] = excl;
        lbase[i0 + 1] = excl + h0;
        __syncthreads();

        // reserve slab run space (zero-based cursor; <=1 atomic/bucket/block)
        for (int i = tid; i < NB; i += 256) {
            int c = hist[i];
            if (c > 0) gbase[i] = i * SLAB + atomicAdd(&cursor[i], c);
        }
        __syncthreads();
        for (int i = tid; i < NBPAD; i += 256) hist[i] = 0;   // -> placement cnt
        __syncthreads();

#pragma unroll
        for (int k = 0; k < 16; ++k) {
            int b = barr[k];
            if (b >= 0) {
                int r = atomicAdd(&hist[b], 1);
                int p = lbase[b] + r;
                sorted[p] = (unsigned)varr[k];
                bId[p] = (unsigned short)b;
            }
        }
        __syncthreads();

        // writeout in sorted order: ~10.5-edge runs -> contiguous addresses
        for (int i = tid; i < nval; i += 256) {
            int b = bId[i];
            pairs[gbase[b] + (i - lbase[b])] = sorted[i];
        }
    } else {
        // ---------------- mm1 path (1 node/thread-quad, round 15 body) ------
        float* sW = (float*)smem;           // first 8 KB of the union
        for (int i = tid; i < D_IN * D_HID; i += 256) sW[i] = W1[i];
        __syncthreads();

        int gid = (blk - SBLOCKS) * 256 + tid;
        int n = gid >> 2;          // node
        int jq = gid & 3;          // output quad
        if (n >= N_NODES) return;

        const float4* f4 = (const float4*)(feat + (size_t)n * D_IN);
        const float4* sW4 = (const float4*)sW;

        float4 acc = make_float4(0.f, 0.f, 0.f, 0.f);
#pragma unroll 8
        for (int kq = 0; kq < 32; ++kq) {
            float4 f = f4[kq];
            int k0 = kq * 4;
            float4 w0 = sW4[(k0 + 0) * 4 + jq];
            float4 w1 = sW4[(k0 + 1) * 4 + jq];
            float4 w2 = sW4[(k0 + 2) * 4 + jq];
            float4 w3 = sW4[(k0 + 3) * 4 + jq];
            acc.x += f.x * w0.x + f.y * w1.x + f.z * w2.x + f.w * w3.x;
            acc.y += f.x * w0.y + f.y * w1.y + f.z * w2.y + f.w * w3.y;
            acc.z += f.x * w0.z + f.y * w1.z + f.z * w2.z + f.w * w3.z;
            acc.w += f.x * w0.w + f.y * w1.w + f.z * w2.w + f.w * w3.w;
        }
        uint2 o;
        o.x = bf_pack(acc.x, acc.y);
        o.y = bf_pack(acc.z, acc.w);
        ((uint2*)(Yu + (size_t)n * 8))[jq] = o;
    }
}

// ---------------------------------------------------------------------------
// K2: per-bucket node sort (256 keys, 1 thread per key). cursor[b] holds the
// bucket count (zero-based). In-place rewrite of pairs -> node-sorted plain
// src ids + node_off (stride-257 layout with per-bucket sentinel).
// ---------------------------------------------------------------------------
__global__ __launch_bounds__(256) void k_nodesort(const int* __restrict__ cursor,
                                                  unsigned* __restrict__ pairs,
                                                  int* __restrict__ node_off) {
    __shared__ unsigned buf[SLAB];      // 18 KB
    __shared__ int hist[BNODES];
    __shared__ int cur[BNODES];
    __shared__ int t[256];

    int tid = threadIdx.x, b = blockIdx.x;
    int beg = b * SLAB;
    int cnt = cursor[b];

    hist[tid] = 0;
    __syncthreads();

    for (int i = tid; i < cnt; i += 256) {
        unsigned p = pairs[beg + i];
        buf[i] = p;
        atomicAdd(&hist[p & (BNODES - 1)], 1);
    }
    __syncthreads();

    int v = hist[tid];
    t[tid] = v;
    __syncthreads();
#pragma unroll
    for (int off = 1; off < 256; off <<= 1) {
        int x = (tid >= off) ? t[tid - off] : 0;
        __syncthreads();
        t[tid] += x;
        __syncthreads();
    }
    int excl = t[tid] - v;
    cur[tid] = excl;
    node_off[b * NOSTRIDE + tid] = beg + excl;
    if (tid == 0) node_off[b * NOSTRIDE + BNODES] = beg + cnt;  // sentinel
    __syncthreads();

    for (int i = tid; i < cnt; i += 256) {
        unsigned p = buf[i];
        int pos = atomicAdd(&cur[p & (BNODES - 1)], 1);
        pairs[beg + pos] = p >> BSHIFT;    // plain src id, node-sorted
    }
}

// ---------------------------------------------------------------------------
// K3: layer-1 aggregation (round 15 verbatim): 64 nodes/block, 4 lanes/node,
// uint2 gathers, simple 8-deep unroll. Fused bias+ReLU -> packed bf16 H1.
// ---------------------------------------------------------------------------
__global__ __launch_bounds__(256) void k_agg1(const int* __restrict__ node_off,
                                              const unsigned* __restrict__ csr,
                                              const uint2* __restrict__ Yu2,
                                              const float* __restrict__ bias1,
                                              uint2* __restrict__ H1u2) {
    int tid = threadIdx.x;
    int g = tid >> 2, c = tid & 3;
    int n = blockIdx.x * 64 + g;
    if (n >= N_NODES) return;
    int idx = n + (n >> 8);
    int beg = node_off[idx], end = node_off[idx + 1];

    float a[4] = {0.f, 0.f, 0.f, 0.f}, b[4] = {0.f, 0.f, 0.f, 0.f};
    int i = beg;
    for (; i + 7 < end; i += 8) {
        unsigned s0 = csr[i],     s1 = csr[i + 1], s2 = csr[i + 2], s3 = csr[i + 3];
        unsigned s4 = csr[i + 4], s5 = csr[i + 5], s6 = csr[i + 6], s7 = csr[i + 7];
        uint2 w0 = Yu2[(size_t)s0 * 4 + c];
        uint2 w1 = Yu2[(size_t)s1 * 4 + c];
        uint2 w2 = Yu2[(size_t)s2 * 4 + c];
        uint2 w3 = Yu2[(size_t)s3 * 4 + c];
        uint2 w4 = Yu2[(size_t)s4 * 4 + c];
        uint2 w5 = Yu2[(size_t)s5 * 4 + c];
        uint2 w6 = Yu2[(size_t)s6 * 4 + c];
        uint2 w7 = Yu2[(size_t)s7 * 4 + c];
        acc4(a, w0); acc4(b, w1); acc4(a, w2); acc4(b, w3);
        acc4(a, w4); acc4(b, w5); acc4(a, w6); acc4(b, w7);
    }
    for (; i < end; ++i) {
        uint2 w = Yu2[(size_t)csr[i] * 4 + c];
        acc4(a, w);
    }
    float f0 = a[0] + b[0] + bias1[c * 4 + 0];
    float f1 = a[1] + b[1] + bias1[c * 4 + 1];
    float f2 = a[2] + b[2] + bias1[c * 4 + 2];
    float f3 = a[3] + b[3] + bias1[c * 4 + 3];
    uint2 o;
    o.x = bf_pack(fmaxf(f0, 0.f), fmaxf(f1, 0.f));
    o.y = bf_pack(fmaxf(f2, 0.f), fmaxf(f3, 0.f));
    H1u2[(size_t)n * 4 + c] = o;
}

// ---------------------------------------------------------------------------
// K4: layer-2 aggregation (round 15 verbatim) + fused mm2 epilogue.
// ---------------------------------------------------------------------------
__global__ __launch_bounds__(256) void k_agg2(const int* __restrict__ node_off,
                                              const unsigned* __restrict__ csr,
                                              const uint2* __restrict__ H1u2,
                                              const float* __restrict__ W2,
                                              const float* __restrict__ b2,
                                              float* __restrict__ out) {
    __shared__ float sacc[64][D_HID + 1];  // 4.4 KB
    __shared__ float sW2[D_HID * D_OUT];   // 2 KB
    __shared__ float sb2[D_OUT];
    int tid = threadIdx.x;
    for (int i2 = tid; i2 < D_HID * D_OUT; i2 += 256) sW2[i2] = W2[i2];
    if (tid < D_OUT) sb2[tid] = b2[tid];

    int g = tid >> 2, c = tid & 3;
    int n = blockIdx.x * 64 + g;

    float a[4] = {0.f, 0.f, 0.f, 0.f}, b[4] = {0.f, 0.f, 0.f, 0.f};
    if (n < N_NODES) {
        int idx = n + (n >> 8);
        int beg = node_off[idx], end = node_off[idx + 1];
        int i = beg;
        for (; i + 7 < end; i += 8) {
            unsigned s0 = csr[i],     s1 = csr[i + 1], s2 = csr[i + 2], s3 = csr[i + 3];
            unsigned s4 = csr[i + 4], s5 = csr[i + 5], s6 = csr[i + 6], s7 = csr[i + 7];
            uint2 w0 = H1u2[(size_t)s0 * 4 + c];
            uint2 w1 = H1u2[(size_t)s1 * 4 + c];
            uint2 w2 = H1u2[(size_t)s2 * 4 + c];
            uint2 w3 = H1u2[(size_t)s3 * 4 + c];
            uint2 w4 = H1u2[(size_t)s4 * 4 + c];
            uint2 w5 = H1u2[(size_t)s5 * 4 + c];
            uint2 w6 = H1u2[(size_t)s6 * 4 + c];
            uint2 w7 = H1u2[(size_t)s7 * 4 + c];
            acc4(a, w0); acc4(b, w1); acc4(a, w2); acc4(b, w3);
            acc4(a, w4); acc4(b, w5); acc4(a, w6); acc4(b, w7);
        }
        for (; i < end; ++i) {
            uint2 w = H1u2[(size_t)csr[i] * 4 + c];
            acc4(a, w);
        }
    }
    sacc[g][c * 4 + 0] = a[0] + b[0];
    sacc[g][c * 4 + 1] = a[1] + b[1];
    sacc[g][c * 4 + 2] = a[2] + b[2];
    sacc[g][c * 4 + 3] = a[3] + b[3];
    __syncthreads();

    // mm2: 64 nodes x 32 outputs = 2048 -> 8 per thread
    for (int t2 = tid; t2 < 64 * D_OUT; t2 += 256) {
        int gg = t2 >> 5, o = t2 & 31;
        int node = blockIdx.x * 64 + gg;
        if (node < N_NODES) {
            float acc = sb2[o];
#pragma unroll
            for (int j = 0; j < D_HID; ++j)
                acc = fmaf(sacc[gg][j], sW2[j * D_OUT + o], acc);
            out[(size_t)node * D_OUT + o] = acc;
        }
    }
}

// ---------------------------------------------------------------------------
extern "C" void kernel_launch(void* const* d_in, const int* in_sizes, int n_in,
                              void* d_out, int out_size, void* d_ws, size_t ws_size,
                              hipStream_t stream) {
    const float* feat = (const float*)d_in[0];
    const int*   src  = (const int*)d_in[1];
    const int*   dst  = (const int*)d_in[2];
    const float* W1   = (const float*)d_in[3];
    const float* b1   = (const float*)d_in[4];
    const float* W2   = (const float*)d_in[5];
    const float* b2   = (const float*)d_in[6];
    float* out = (float*)d_out;

    // ws layout (~14.0 MB):
    //   [0        , 7206912 )  pairs/csr slabs (NB * SLAB u32)
    //   [7208960  , +3.2M   )  Yu   (bf16x16 rows, packed, 16B aligned)
    //   [10408960 , +3.2M   )  H1u  (bf16x16 rows, packed, 16B aligned)
    //   [13608960 , +1.6K   )  cursor   (NB ints, zero-based counts)
    //   [13613056 , +402K   )  node_off (NB*257 ints)
    char* base = (char*)d_ws;
    unsigned* pairs    = (unsigned*)(base);
    unsigned* Yu       = (unsigned*)(base + 7208960);
    unsigned* H1u      = (unsigned*)(base + 10408960);
    int*      cursor   = (int*)(base + 13608960);
    int*      node_off = (int*)(base + 13613056);

    // cursor zeroing (1.6 KB, ~2us in-graph)
    hipMemsetAsync(cursor, 0, NB * sizeof(int), stream);

    // K1: fused sortscatter (391 blocks) + mm1 (1563 blocks, 1 node/thr-quad)
    k_fused1  <<<SBLOCKS + MMBLOCKS, 256, 0, stream>>>(feat, W1, src, dst,
                                                       cursor, pairs, Yu);
    // K2: per-bucket node sort -> csr + node_off
    k_nodesort<<<NB, 256, 0, stream>>>(cursor, pairs, node_off);
    // K3: layer-1 aggregation (fused bias+ReLU)
    k_agg1    <<<(N_NODES + 63) / 64, 256, 0, stream>>>(node_off, pairs,
                                                        (const uint2*)Yu, b1,
                                                        (uint2*)H1u);
    // K4: layer-2 aggregation + fused mm2
    k_agg2    <<<(N_NODES + 63) / 64, 256, 0, stream>>>(node_off, pairs,
                                                        (const uint2*)H1u, W2, b2, out);
}

// Round 17
// 83.714 us; speedup vs baseline: 1.1855x; 1.0718x over previous
//
#include <hip/hip_runtime.h>
#include <hip/hip_bf16.h>

#define N_NODES 100000
#define N_EDGES 1600000
#define D_IN    128
#define D_HID   16
#define D_OUT   32

#define BSHIFT 8
#define BNODES 256                 // nodes per bucket
#define NB 391                     // ceil(100000/256)
#define NBPAD 512
#define SCHUNK 4096                // edges per sort block
#define SBLOCKS 391                // ceil(1600000/4096)
#define MMBLOCKS 1563              // mm1: 1 node/thread-quad (proven)
#define SLAB 4608                  // slab slots per bucket (mean 4096, +8 sigma)
#define NOSTRIDE 257               // node_off stride per bucket (256 + sentinel)

// shared-memory union layout for the fused kernel (bytes)
#define SS_HIST   0                // int[512]
#define SS_LBASE  2048             // int[512]
#define SS_GBASE  4096             // int[391] (pad to 1600)
#define SS_TSCAN  5696             // int[256]
#define SS_SORTED 6720             // unsigned[4096]
#define SS_BID    23104            // ushort[4096]
#define SS_BYTES  31296            // 31.3 KB -> 5 blocks/CU

// bf16x2 helpers -------------------------------------------------------------
__device__ inline float bf_lo(unsigned dw) { return __uint_as_float(dw << 16); }
__device__ inline float bf_hi(unsigned dw) { return __uint_as_float(dw & 0xffff0000u); }
__device__ inline unsigned bf_pack(float f0, float f1) {
    union { __hip_bfloat16 h[2]; unsigned u; } pu;
    pu.h[0] = __float2bfloat16(f0);
    pu.h[1] = __float2bfloat16(f1);
    return pu.u;
}
__device__ inline void acc4(float* a, uint2 w) {
    a[0] += bf_lo(w.x); a[1] += bf_hi(w.x);
    a[2] += bf_lo(w.y); a[3] += bf_hi(w.y);
}

// ---------------------------------------------------------------------------
// K1 (fused, round 16 proven): blocks [0, SBLOCKS) = bucket-grouping counting
// sort (zero-based slab cursors); blocks [SBLOCKS, ..) = mm1 at 1 node/
// thread-quad. Disjoint inputs, complementary bottlenecks, co-resident.
// ---------------------------------------------------------------------------
__global__ __launch_bounds__(256) void k_fused1(const float* __restrict__ feat,
                                                const float* __restrict__ W1,
                                                const int* __restrict__ src,
                                                const int* __restrict__ dst,
                                                int* __restrict__ cursor,
                                                unsigned* __restrict__ pairs,
                                                unsigned* __restrict__ Yu) {
    __shared__ __align__(16) char smem[SS_BYTES];
    int tid = threadIdx.x, blk = blockIdx.x;

    if (blk < SBLOCKS) {
        // ---------------- sortscatter path ----------------
        int* hist    = (int*)(smem + SS_HIST);
        int* lbase   = (int*)(smem + SS_LBASE);
        int* gbase   = (int*)(smem + SS_GBASE);
        int* tscan   = (int*)(smem + SS_TSCAN);
        unsigned* sorted = (unsigned*)(smem + SS_SORTED);
        unsigned short* bId = (unsigned short*)(smem + SS_BID);

        int base = blk * SCHUNK;
        int nval = N_EDGES - base;
        if (nval > SCHUNK) nval = SCHUNK;

        for (int i = tid; i < NBPAD; i += 256) hist[i] = 0;
        __syncthreads();

        int varr[16], barr[16];
#pragma unroll
        for (int k = 0; k < 16; ++k) {
            int e = base + k * 256 + tid;
            if (e < N_EDGES) {
                int s = src[e], d = dst[e];
                varr[k] = (s << BSHIFT) | (d & (BNODES - 1));
                int b = d >> BSHIFT;
                barr[k] = b;
                atomicAdd(&hist[b], 1);
            } else {
                barr[k] = -1;
            }
        }
        __syncthreads();

        int i0 = tid * 2;
        int h0 = hist[i0], h1 = hist[i0 + 1];
        int lsum = h0 + h1;
        tscan[tid] = lsum;
        __syncthreads();
#pragma unroll
        for (int off = 1; off < 256; off <<= 1) {
            int x = (tid >= off) ? tscan[tid - off] : 0;
            __syncthreads();
            tscan[tid] += x;
            __syncthreads();
        }
        int excl = tscan[tid] - lsum;
        lbase[i0 + 0] = excl;
        lbase[i0 + 1] = excl + h0;
        __syncthreads();

        for (int i = tid; i < NB; i += 256) {
            int c = hist[i];
            if (c > 0) gbase[i] = i * SLAB + atomicAdd(&cursor[i], c);
        }
        __syncthreads();
        for (int i = tid; i < NBPAD; i += 256) hist[i] = 0;   // -> placement cnt
        __syncthreads();

#pragma unroll
        for (int k = 0; k < 16; ++k) {
            int b = barr[k];
            if (b >= 0) {
                int r = atomicAdd(&hist[b], 1);
                int p = lbase[b] + r;
                sorted[p] = (unsigned)varr[k];
                bId[p] = (unsigned short)b;
            }
        }
        __syncthreads();

        for (int i = tid; i < nval; i += 256) {
            int b = bId[i];
            pairs[gbase[b] + (i - lbase[b])] = sorted[i];
        }
    } else {
        // ---------------- mm1 path (1 node/thread-quad) ----------------
        float* sW = (float*)smem;           // first 8 KB of the union
        for (int i = tid; i < D_IN * D_HID; i += 256) sW[i] = W1[i];
        __syncthreads();

        int gid = (blk - SBLOCKS) * 256 + tid;
        int n = gid >> 2;          // node
        int jq = gid & 3;          // output quad
        if (n >= N_NODES) return;

        const float4* f4 = (const float4*)(feat + (size_t)n * D_IN);
        const float4* sW4 = (const float4*)sW;

        float4 acc = make_float4(0.f, 0.f, 0.f, 0.f);
#pragma unroll 8
        for (int kq = 0; kq < 32; ++kq) {
            float4 f = f4[kq];
            int k0 = kq * 4;
            float4 w0 = sW4[(k0 + 0) * 4 + jq];
            float4 w1 = sW4[(k0 + 1) * 4 + jq];
            float4 w2 = sW4[(k0 + 2) * 4 + jq];
            float4 w3 = sW4[(k0 + 3) * 4 + jq];
            acc.x += f.x * w0.x + f.y * w1.x + f.z * w2.x + f.w * w3.x;
            acc.y += f.x * w0.y + f.y * w1.y + f.z * w2.y + f.w * w3.y;
            acc.z += f.x * w0.z + f.y * w1.z + f.z * w2.z + f.w * w3.z;
            acc.w += f.x * w0.w + f.y * w1.w + f.z * w2.w + f.w * w3.w;
        }
        uint2 o;
        o.x = bf_pack(acc.x, acc.y);
        o.y = bf_pack(acc.z, acc.w);
        ((uint2*)(Yu + (size_t)n * 8))[jq] = o;
    }
}

// ---------------------------------------------------------------------------
// K2 (merged): per-bucket node sort + layer-1 aggregation, 1024 threads.
// Phase 1: counting sort of the bucket's edges by node (LDS), write csr +
// node_off for agg2. Phase 2: 4 lanes/node x 256 nodes = 1024 threads gather
// Yu rows over each node's sorted run (bounds from LDS). Saves the nodesort
// launch, the csr re-read, and node_off reads on the agg1 side.
// ---------------------------------------------------------------------------
__global__ __launch_bounds__(1024) void k_sortagg1(const int* __restrict__ cursor,
                                                   unsigned* __restrict__ pairs,
                                                   const uint2* __restrict__ Yu2,
                                                   const float* __restrict__ bias1,
                                                   uint2* __restrict__ H1u2,
                                                   int* __restrict__ node_off) {
    __shared__ unsigned buf[SLAB];      // 18 KB
    __shared__ int hist[BNODES];        // 1 KB
    __shared__ int lbase[BNODES];
    __shared__ int cur[BNODES];
    __shared__ int t[BNODES];
    __shared__ float sB[D_HID];

    int tid = threadIdx.x, b = blockIdx.x;
    int beg = b * SLAB;
    int cnt = cursor[b];

    if (tid < BNODES) hist[tid] = 0;
    if (tid < D_HID) sB[tid] = bias1[tid];
    __syncthreads();

    for (int i = tid; i < cnt; i += 1024) {
        unsigned p = pairs[beg + i];
        buf[i] = p;
        atomicAdd(&hist[p & (BNODES - 1)], 1);
    }
    __syncthreads();

    // exclusive scan over 256 keys (threads 0..255 active)
    if (tid < BNODES) t[tid] = hist[tid];
    __syncthreads();
#pragma unroll
    for (int off = 1; off < BNODES; off <<= 1) {
        int x = 0;
        if (tid < BNODES && tid >= off) x = t[tid - off];
        __syncthreads();
        if (tid < BNODES) t[tid] += x;
        __syncthreads();
    }
    if (tid < BNODES) {
        int excl = t[tid] - hist[tid];
        lbase[tid] = excl;
        cur[tid] = excl;
        node_off[b * NOSTRIDE + tid] = beg + excl;
        if (tid == 0) node_off[b * NOSTRIDE + BNODES] = beg + cnt;
    }
    __syncthreads();

    // place: rewrite pairs as node-sorted plain src ids (global, L2-hot)
    for (int i = tid; i < cnt; i += 1024) {
        unsigned p = buf[i];
        int pos = atomicAdd(&cur[p & (BNODES - 1)], 1);
        pairs[beg + pos] = p >> BSHIFT;
    }
    __syncthreads();   // global writes visible block-wide after barrier

    // phase 2: aggregate. 4 lanes/node; run bounds from LDS.
    int g = tid >> 2, c = tid & 3;
    int n = b * BNODES + g;
    if (n >= N_NODES) return;
    int i = beg + lbase[g];
    int e = beg + cur[g];              // cur = lbase + count after placement
    const unsigned* csr = pairs;

    float a[4] = {0.f, 0.f, 0.f, 0.f}, bb[4] = {0.f, 0.f, 0.f, 0.f};
    for (; i + 7 < e; i += 8) {
        unsigned s0 = csr[i],     s1 = csr[i + 1], s2 = csr[i + 2], s3 = csr[i + 3];
        unsigned s4 = csr[i + 4], s5 = csr[i + 5], s6 = csr[i + 6], s7 = csr[i + 7];
        uint2 w0 = Yu2[(size_t)s0 * 4 + c];
        uint2 w1 = Yu2[(size_t)s1 * 4 + c];
        uint2 w2 = Yu2[(size_t)s2 * 4 + c];
        uint2 w3 = Yu2[(size_t)s3 * 4 + c];
        uint2 w4 = Yu2[(size_t)s4 * 4 + c];
        uint2 w5 = Yu2[(size_t)s5 * 4 + c];
        uint2 w6 = Yu2[(size_t)s6 * 4 + c];
        uint2 w7 = Yu2[(size_t)s7 * 4 + c];
        acc4(a, w0); acc4(bb, w1); acc4(a, w2); acc4(bb, w3);
        acc4(a, w4); acc4(bb, w5); acc4(a, w6); acc4(bb, w7);
    }
    for (; i + 3 < e; i += 4) {        // 4-deep mid-tail
        unsigned s0 = csr[i], s1 = csr[i + 1], s2 = csr[i + 2], s3 = csr[i + 3];
        uint2 w0 = Yu2[(size_t)s0 * 4 + c];
        uint2 w1 = Yu2[(size_t)s1 * 4 + c];
        uint2 w2 = Yu2[(size_t)s2 * 4 + c];
        uint2 w3 = Yu2[(size_t)s3 * 4 + c];
        acc4(a, w0); acc4(bb, w1); acc4(a, w2); acc4(bb, w3);
    }
    for (; i < e; ++i) {
        uint2 w = Yu2[(size_t)csr[i] * 4 + c];
        acc4(a, w);
    }
    float f0 = a[0] + bb[0] + sB[c * 4 + 0];
    float f1 = a[1] + bb[1] + sB[c * 4 + 1];
    float f2 = a[2] + bb[2] + sB[c * 4 + 2];
    float f3 = a[3] + bb[3] + sB[c * 4 + 3];
    uint2 o;
    o.x = bf_pack(fmaxf(f0, 0.f), fmaxf(f1, 0.f));
    o.y = bf_pack(fmaxf(f2, 0.f), fmaxf(f3, 0.f));
    H1u2[(size_t)n * 4 + c] = o;
}

// ---------------------------------------------------------------------------
// K3: layer-2 aggregation + fused mm2 epilogue (round 15/16 structure,
// + 4-deep mid-tail).
// ---------------------------------------------------------------------------
__global__ __launch_bounds__(256) void k_agg2(const int* __restrict__ node_off,
                                              const unsigned* __restrict__ csr,
                                              const uint2* __restrict__ H1u2,
                                              const float* __restrict__ W2,
                                              const float* __restrict__ b2,
                                              float* __restrict__ out) {
    __shared__ float sacc[64][D_HID + 1];  // 4.4 KB
    __shared__ float sW2[D_HID * D_OUT];   // 2 KB
    __shared__ float sb2[D_OUT];
    int tid = threadIdx.x;
    for (int i2 = tid; i2 < D_HID * D_OUT; i2 += 256) sW2[i2] = W2[i2];
    if (tid < D_OUT) sb2[tid] = b2[tid];

    int g = tid >> 2, c = tid & 3;
    int n = blockIdx.x * 64 + g;

    float a[4] = {0.f, 0.f, 0.f, 0.f}, bb[4] = {0.f, 0.f, 0.f, 0.f};
    if (n < N_NODES) {
        int idx = n + (n >> 8);
        int i = node_off[idx], e = node_off[idx + 1];
        for (; i + 7 < e; i += 8) {
            unsigned s0 = csr[i],     s1 = csr[i + 1], s2 = csr[i + 2], s3 = csr[i + 3];
            unsigned s4 = csr[i + 4], s5 = csr[i + 5], s6 = csr[i + 6], s7 = csr[i + 7];
            uint2 w0 = H1u2[(size_t)s0 * 4 + c];
            uint2 w1 = H1u2[(size_t)s1 * 4 + c];
            uint2 w2 = H1u2[(size_t)s2 * 4 + c];
            uint2 w3 = H1u2[(size_t)s3 * 4 + c];
            uint2 w4 = H1u2[(size_t)s4 * 4 + c];
            uint2 w5 = H1u2[(size_t)s5 * 4 + c];
            uint2 w6 = H1u2[(size_t)s6 * 4 + c];
            uint2 w7 = H1u2[(size_t)s7 * 4 + c];
            acc4(a, w0); acc4(bb, w1); acc4(a, w2); acc4(bb, w3);
            acc4(a, w4); acc4(bb, w5); acc4(a, w6); acc4(bb, w7);
        }
        for (; i + 3 < e; i += 4) {    // 4-deep mid-tail
            unsigned s0 = csr[i], s1 = csr[i + 1], s2 = csr[i + 2], s3 = csr[i + 3];
            uint2 w0 = H1u2[(size_t)s0 * 4 + c];
            uint2 w1 = H1u2[(size_t)s1 * 4 + c];
            uint2 w2 = H1u2[(size_t)s2 * 4 + c];
            uint2 w3 = H1u2[(size_t)s3 * 4 + c];
            acc4(a, w0); acc4(bb, w1); acc4(a, w2); acc4(bb, w3);
        }
        for (; i < e; ++i) {
            uint2 w = H1u2[(size_t)csr[i] * 4 + c];
            acc4(a, w);
        }
    }
    sacc[g][c * 4 + 0] = a[0] + bb[0];
    sacc[g][c * 4 + 1] = a[1] + bb[1];
    sacc[g][c * 4 + 2] = a[2] + bb[2];
    sacc[g][c * 4 + 3] = a[3] + bb[3];
    __syncthreads();

    // mm2: 64 nodes x 32 outputs = 2048 -> 8 per thread
    for (int t2 = tid; t2 < 64 * D_OUT; t2 += 256) {
        int gg = t2 >> 5, o = t2 & 31;
        int node = blockIdx.x * 64 + gg;
        if (node < N_NODES) {
            float acc = sb2[o];
#pragma unroll
            for (int j = 0; j < D_HID; ++j)
                acc = fmaf(sacc[gg][j], sW2[j * D_OUT + o], acc);
            out[(size_t)node * D_OUT + o] = acc;
        }
    }
}

// ---------------------------------------------------------------------------
extern "C" void kernel_launch(void* const* d_in, const int* in_sizes, int n_in,
                              void* d_out, int out_size, void* d_ws, size_t ws_size,
                              hipStream_t stream) {
    const float* feat = (const float*)d_in[0];
    const int*   src  = (const int*)d_in[1];
    const int*   dst  = (const int*)d_in[2];
    const float* W1   = (const float*)d_in[3];
    const float* b1   = (const float*)d_in[4];
    const float* W2   = (const float*)d_in[5];
    const float* b2   = (const float*)d_in[6];
    float* out = (float*)d_out;

    // ws layout (~14.0 MB):
    //   [0        , 7206912 )  pairs/csr slabs (NB * SLAB u32)
    //   [7208960  , +3.2M   )  Yu   (bf16x16 rows, packed, 16B aligned)
    //   [10408960 , +3.2M   )  H1u  (bf16x16 rows, packed, 16B aligned)
    //   [13608960 , +1.6K   )  cursor   (NB ints, zero-based counts)
    //   [13613056 , +402K   )  node_off (NB*257 ints)
    char* base = (char*)d_ws;
    unsigned* pairs    = (unsigned*)(base);
    unsigned* Yu       = (unsigned*)(base + 7208960);
    unsigned* H1u      = (unsigned*)(base + 10408960);
    int*      cursor   = (int*)(base + 13608960);
    int*      node_off = (int*)(base + 13613056);

    // cursor zeroing (1.6 KB)
    hipMemsetAsync(cursor, 0, NB * sizeof(int), stream);

    // K1: fused sortscatter (391 blocks) + mm1 (1563 blocks)
    k_fused1   <<<SBLOCKS + MMBLOCKS, 256, 0, stream>>>(feat, W1, src, dst,
                                                        cursor, pairs, Yu);
    // K2: merged node sort + layer-1 aggregation (1024 threads/bucket)
    k_sortagg1 <<<NB, 1024, 0, stream>>>(cursor, pairs, (const uint2*)Yu, b1,
                                         (uint2*)H1u, node_off);
    // K3: layer-2 aggregation + fused mm2
    k_agg2     <<<(N_NODES + 63) / 64, 256, 0, stream>>>(node_off, pairs,
                                                         (const uint2*)H1u, W2, b2, out);
}

// Round 18
// 80.832 us; speedup vs baseline: 1.2278x; 1.0357x over previous
//
#include <hip/hip_runtime.h>
#include <hip/hip_bf16.h>

#define N_NODES 100000
#define N_EDGES 1600000
#define D_IN    128
#define D_HID   16
#define D_OUT   32

#define BSHIFT 8
#define BNODES 256                 // nodes per bucket
#define NB 391                     // ceil(100000/256)
#define NBPAD 512
#define SCHUNK 4096                // edges per sort block
#define SBLOCKS 391                // ceil(1600000/4096)
#define MMBLOCKS 1563              // mm1: 1 node/thread-quad (proven)
#define SLAB 4608                  // slab slots per bucket (mean 4096, +8 sigma)
#define NOSTRIDE 257               // node_off stride per bucket (256 + sentinel)

// shared-memory union layout for the fused kernel (bytes)
#define SS_HIST   0                // int[512]
#define SS_LBASE  2048             // int[512]
#define SS_GBASE  4096             // int[391] (pad to 1600)
#define SS_TSCAN  5696             // int[256]
#define SS_SORTED 6720             // unsigned[4096]
#define SS_BID    23104            // ushort[4096]
#define SS_BYTES  31296            // 31.3 KB -> 5 blocks/CU

// bf16x2 helpers -------------------------------------------------------------
__device__ inline float bf_lo(unsigned dw) { return __uint_as_float(dw << 16); }
__device__ inline float bf_hi(unsigned dw) { return __uint_as_float(dw & 0xffff0000u); }
__device__ inline unsigned bf_pack(float f0, float f1) {
    union { __hip_bfloat16 h[2]; unsigned u; } pu;
    pu.h[0] = __float2bfloat16(f0);
    pu.h[1] = __float2bfloat16(f1);
    return pu.u;
}
__device__ inline void acc4(float* a, uint2 w) {
    a[0] += bf_lo(w.x); a[1] += bf_hi(w.x);
    a[2] += bf_lo(w.y); a[3] += bf_hi(w.y);
}

// ---------------------------------------------------------------------------
// K1 (fused, proven r16/r17): blocks [0, SBLOCKS) = bucket-grouping counting
// sort (zero-based slab cursors); blocks [SBLOCKS, ..) = mm1 at 1 node/
// thread-quad. Disjoint inputs, complementary bottlenecks, co-resident.
// ---------------------------------------------------------------------------
__global__ __launch_bounds__(256) void k_fused1(const float* __restrict__ feat,
                                                const float* __restrict__ W1,
                                                const int* __restrict__ src,
                                                const int* __restrict__ dst,
                                                int* __restrict__ cursor,
                                                unsigned* __restrict__ pairs,
                                                unsigned* __restrict__ Yu) {
    __shared__ __align__(16) char smem[SS_BYTES];
    int tid = threadIdx.x, blk = blockIdx.x;

    if (blk < SBLOCKS) {
        // ---------------- sortscatter path ----------------
        int* hist    = (int*)(smem + SS_HIST);
        int* lbase   = (int*)(smem + SS_LBASE);
        int* gbase   = (int*)(smem + SS_GBASE);
        int* tscan   = (int*)(smem + SS_TSCAN);
        unsigned* sorted = (unsigned*)(smem + SS_SORTED);
        unsigned short* bId = (unsigned short*)(smem + SS_BID);

        int base = blk * SCHUNK;
        int nval = N_EDGES - base;
        if (nval > SCHUNK) nval = SCHUNK;

        for (int i = tid; i < NBPAD; i += 256) hist[i] = 0;
        __syncthreads();

        int varr[16], barr[16];
#pragma unroll
        for (int k = 0; k < 16; ++k) {
            int e = base + k * 256 + tid;
            if (e < N_EDGES) {
                int s = src[e], d = dst[e];
                varr[k] = (s << BSHIFT) | (d & (BNODES - 1));
                int b = d >> BSHIFT;
                barr[k] = b;
                atomicAdd(&hist[b], 1);
            } else {
                barr[k] = -1;
            }
        }
        __syncthreads();

        int i0 = tid * 2;
        int h0 = hist[i0], h1 = hist[i0 + 1];
        int lsum = h0 + h1;
        tscan[tid] = lsum;
        __syncthreads();
#pragma unroll
        for (int off = 1; off < 256; off <<= 1) {
            int x = (tid >= off) ? tscan[tid - off] : 0;
            __syncthreads();
            tscan[tid] += x;
            __syncthreads();
        }
        int excl = tscan[tid] - lsum;
        lbase[i0 + 0] = excl;
        lbase[i0 + 1] = excl + h0;
        __syncthreads();

        for (int i = tid; i < NB; i += 256) {
            int c = hist[i];
            if (c > 0) gbase[i] = i * SLAB + atomicAdd(&cursor[i], c);
        }
        __syncthreads();
        for (int i = tid; i < NBPAD; i += 256) hist[i] = 0;   // -> placement cnt
        __syncthreads();

#pragma unroll
        for (int k = 0; k < 16; ++k) {
            int b = barr[k];
            if (b >= 0) {
                int r = atomicAdd(&hist[b], 1);
                int p = lbase[b] + r;
                sorted[p] = (unsigned)varr[k];
                bId[p] = (unsigned short)b;
            }
        }
        __syncthreads();

        for (int i = tid; i < nval; i += 256) {
            int b = bId[i];
            pairs[gbase[b] + (i - lbase[b])] = sorted[i];
        }
    } else {
        // ---------------- mm1 path (1 node/thread-quad) ----------------
        float* sW = (float*)smem;           // first 8 KB of the union
        for (int i = tid; i < D_IN * D_HID; i += 256) sW[i] = W1[i];
        __syncthreads();

        int gid = (blk - SBLOCKS) * 256 + tid;
        int n = gid >> 2;          // node
        int jq = gid & 3;          // output quad
        if (n >= N_NODES) return;

        const float4* f4 = (const float4*)(feat + (size_t)n * D_IN);
        const float4* sW4 = (const float4*)sW;

        float4 acc = make_float4(0.f, 0.f, 0.f, 0.f);
#pragma unroll 8
        for (int kq = 0; kq < 32; ++kq) {
            float4 f = f4[kq];
            int k0 = kq * 4;
            float4 w0 = sW4[(k0 + 0) * 4 + jq];
            float4 w1 = sW4[(k0 + 1) * 4 + jq];
            float4 w2 = sW4[(k0 + 2) * 4 + jq];
            float4 w3 = sW4[(k0 + 3) * 4 + jq];
            acc.x += f.x * w0.x + f.y * w1.x + f.z * w2.x + f.w * w3.x;
            acc.y += f.x * w0.y + f.y * w1.y + f.z * w2.y + f.w * w3.y;
            acc.z += f.x * w0.z + f.y * w1.z + f.z * w2.z + f.w * w3.z;
            acc.w += f.x * w0.w + f.y * w1.w + f.z * w2.w + f.w * w3.w;
        }
        uint2 o;
        o.x = bf_pack(acc.x, acc.y);
        o.y = bf_pack(acc.z, acc.w);
        ((uint2*)(Yu + (size_t)n * 8))[jq] = o;
    }
}

// ---------------------------------------------------------------------------
// K2 (merged): per-bucket node sort + layer-1 aggregation, 1024 threads.
// Phase 1: counting sort; sorted src ids kept in LDS (sbuf) AND written to
// global csr (for agg2). Phase 2: 4 lanes/node gather Yu rows with indices
// read from LDS (ds_read on the LGKM pipe -> zero index VMEM instructions,
// and no dependence on the global csr writeback).
// LDS ~40.5 KB -> 2 blocks/CU at 1024 threads (the residency cap anyway).
// ---------------------------------------------------------------------------
__global__ __launch_bounds__(1024) void k_sortagg1(const int* __restrict__ cursor,
                                                   unsigned* __restrict__ pairs,
                                                   const uint2* __restrict__ Yu2,
                                                   const float* __restrict__ bias1,
                                                   uint2* __restrict__ H1u2,
                                                   int* __restrict__ node_off) {
    __shared__ unsigned buf[SLAB];      // 18 KB
    __shared__ unsigned sbuf[SLAB];     // 18 KB (node-sorted src ids)
    __shared__ int hist[BNODES];        // 1 KB
    __shared__ int lbase[BNODES];
    __shared__ int cur[BNODES];
    __shared__ int t[BNODES];
    __shared__ float sB[D_HID];

    int tid = threadIdx.x, b = blockIdx.x;
    int beg = b * SLAB;
    int cnt = cursor[b];

    if (tid < BNODES) hist[tid] = 0;
    if (tid < D_HID) sB[tid] = bias1[tid];
    __syncthreads();

    for (int i = tid; i < cnt; i += 1024) {
        unsigned p = pairs[beg + i];
        buf[i] = p;
        atomicAdd(&hist[p & (BNODES - 1)], 1);
    }
    __syncthreads();

    // exclusive scan over 256 keys (threads 0..255 active)
    if (tid < BNODES) t[tid] = hist[tid];
    __syncthreads();
#pragma unroll
    for (int off = 1; off < BNODES; off <<= 1) {
        int x = 0;
        if (tid < BNODES && tid >= off) x = t[tid - off];
        __syncthreads();
        if (tid < BNODES) t[tid] += x;
        __syncthreads();
    }
    if (tid < BNODES) {
        int excl = t[tid] - hist[tid];
        lbase[tid] = excl;
        cur[tid] = excl;
        node_off[b * NOSTRIDE + tid] = beg + excl;
        if (tid == 0) node_off[b * NOSTRIDE + BNODES] = beg + cnt;
    }
    __syncthreads();

    // place: sorted src ids into LDS sbuf + global csr (for agg2)
    for (int i = tid; i < cnt; i += 1024) {
        unsigned p = buf[i];
        int pos = atomicAdd(&cur[p & (BNODES - 1)], 1);
        unsigned sid = p >> BSHIFT;
        sbuf[pos] = sid;
        pairs[beg + pos] = sid;
    }
    __syncthreads();

    // phase 2: aggregate; indices from LDS (LGKM pipe, overlaps gathers)
    int g = tid >> 2, c = tid & 3;
    int n = b * BNODES + g;
    if (n >= N_NODES) return;
    int i = lbase[g];
    int e = cur[g];                    // cur = lbase + count after placement

    float a[4] = {0.f, 0.f, 0.f, 0.f}, bb[4] = {0.f, 0.f, 0.f, 0.f};
    for (; i + 7 < e; i += 8) {
        unsigned s0 = sbuf[i],     s1 = sbuf[i + 1], s2 = sbuf[i + 2], s3 = sbuf[i + 3];
        unsigned s4 = sbuf[i + 4], s5 = sbuf[i + 5], s6 = sbuf[i + 6], s7 = sbuf[i + 7];
        uint2 w0 = Yu2[(size_t)s0 * 4 + c];
        uint2 w1 = Yu2[(size_t)s1 * 4 + c];
        uint2 w2 = Yu2[(size_t)s2 * 4 + c];
        uint2 w3 = Yu2[(size_t)s3 * 4 + c];
        uint2 w4 = Yu2[(size_t)s4 * 4 + c];
        uint2 w5 = Yu2[(size_t)s5 * 4 + c];
        uint2 w6 = Yu2[(size_t)s6 * 4 + c];
        uint2 w7 = Yu2[(size_t)s7 * 4 + c];
        acc4(a, w0); acc4(bb, w1); acc4(a, w2); acc4(bb, w3);
        acc4(a, w4); acc4(bb, w5); acc4(a, w6); acc4(bb, w7);
    }
    for (; i + 3 < e; i += 4) {        // 4-deep mid-tail
        unsigned s0 = sbuf[i], s1 = sbuf[i + 1], s2 = sbuf[i + 2], s3 = sbuf[i + 3];
        uint2 w0 = Yu2[(size_t)s0 * 4 + c];
        uint2 w1 = Yu2[(size_t)s1 * 4 + c];
        uint2 w2 = Yu2[(size_t)s2 * 4 + c];
        uint2 w3 = Yu2[(size_t)s3 * 4 + c];
        acc4(a, w0); acc4(bb, w1); acc4(a, w2); acc4(bb, w3);
    }
    for (; i < e; ++i) {
        uint2 w = Yu2[(size_t)sbuf[i] * 4 + c];
        acc4(a, w);
    }
    float f0 = a[0] + bb[0] + sB[c * 4 + 0];
    float f1 = a[1] + bb[1] + sB[c * 4 + 1];
    float f2 = a[2] + bb[2] + sB[c * 4 + 2];
    float f3 = a[3] + bb[3] + sB[c * 4 + 3];
    uint2 o;
    o.x = bf_pack(fmaxf(f0, 0.f), fmaxf(f1, 0.f));
    o.y = bf_pack(fmaxf(f2, 0.f), fmaxf(f3, 0.f));
    H1u2[(size_t)n * 4 + c] = o;
}

// ---------------------------------------------------------------------------
// K3: layer-2 aggregation + fused mm2 epilogue. Index loads vectorized as
// uint4 (2 VMEM instrs per 8 edges instead of 8): align run start to 4 with
// a <=3-edge scalar prologue, then 16B-aligned uint4 chunks.
// ---------------------------------------------------------------------------
__global__ __launch_bounds__(256) void k_agg2(const int* __restrict__ node_off,
                                              const unsigned* __restrict__ csr,
                                              const uint2* __restrict__ H1u2,
                                              const float* __restrict__ W2,
                                              const float* __restrict__ b2,
                                              float* __restrict__ out) {
    __shared__ float sacc[64][D_HID + 1];  // 4.4 KB
    __shared__ float sW2[D_HID * D_OUT];   // 2 KB
    __shared__ float sb2[D_OUT];
    int tid = threadIdx.x;
    for (int i2 = tid; i2 < D_HID * D_OUT; i2 += 256) sW2[i2] = W2[i2];
    if (tid < D_OUT) sb2[tid] = b2[tid];

    int g = tid >> 2, c = tid & 3;
    int n = blockIdx.x * 64 + g;

    float a[4] = {0.f, 0.f, 0.f, 0.f}, bb[4] = {0.f, 0.f, 0.f, 0.f};
    if (n < N_NODES) {
        int idx = n + (n >> 8);
        int i = node_off[idx], e = node_off[idx + 1];
        // prologue: align i to 4 (csr slab base is 16B aligned)
        for (; i < e && (i & 3); ++i) {
            uint2 w = H1u2[(size_t)csr[i] * 4 + c];
            acc4(a, w);
        }
        for (; i + 7 < e; i += 8) {
            uint4 iv0 = *(const uint4*)(csr + i);
            uint4 iv1 = *(const uint4*)(csr + i + 4);
            uint2 w0 = H1u2[(size_t)iv0.x * 4 + c];
            uint2 w1 = H1u2[(size_t)iv0.y * 4 + c];
            uint2 w2 = H1u2[(size_t)iv0.z * 4 + c];
            uint2 w3 = H1u2[(size_t)iv0.w * 4 + c];
            uint2 w4 = H1u2[(size_t)iv1.x * 4 + c];
            uint2 w5 = H1u2[(size_t)iv1.y * 4 + c];
            uint2 w6 = H1u2[(size_t)iv1.z * 4 + c];
            uint2 w7 = H1u2[(size_t)iv1.w * 4 + c];
            acc4(a, w0); acc4(bb, w1); acc4(a, w2); acc4(bb, w3);
            acc4(a, w4); acc4(bb, w5); acc4(a, w6); acc4(bb, w7);
        }
        for (; i + 3 < e; i += 4) {
            uint4 iv = *(const uint4*)(csr + i);
            uint2 w0 = H1u2[(size_t)iv.x * 4 + c];
            uint2 w1 = H1u2[(size_t)iv.y * 4 + c];
            uint2 w2 = H1u2[(size_t)iv.z * 4 + c];
            uint2 w3 = H1u2[(size_t)iv.w * 4 + c];
            acc4(a, w0); acc4(bb, w1); acc4(a, w2); acc4(bb, w3);
        }
        for (; i < e; ++i) {
            uint2 w = H1u2[(size_t)csr[i] * 4 + c];
            acc4(a, w);
        }
    }
    sacc[g][c * 4 + 0] = a[0] + bb[0];
    sacc[g][c * 4 + 1] = a[1] + bb[1];
    sacc[g][c * 4 + 2] = a[2] + bb[2];
    sacc[g][c * 4 + 3] = a[3] + bb[3];
    __syncthreads();

    // mm2: 64 nodes x 32 outputs = 2048 -> 8 per thread
    for (int t2 = tid; t2 < 64 * D_OUT; t2 += 256) {
        int gg = t2 >> 5, o = t2 & 31;
        int node = blockIdx.x * 64 + gg;
        if (node < N_NODES) {
            float acc = sb2[o];
#pragma unroll
            for (int j = 0; j < D_HID; ++j)
                acc = fmaf(sacc[gg][j], sW2[j * D_OUT + o], acc);
            out[(size_t)node * D_OUT + o] = acc;
        }
    }
}

// ---------------------------------------------------------------------------
extern "C" void kernel_launch(void* const* d_in, const int* in_sizes, int n_in,
                              void* d_out, int out_size, void* d_ws, size_t ws_size,
                              hipStream_t stream) {
    const float* feat = (const float*)d_in[0];
    const int*   src  = (const int*)d_in[1];
    const int*   dst  = (const int*)d_in[2];
    const float* W1   = (const float*)d_in[3];
    const float* b1   = (const float*)d_in[4];
    const float* W2   = (const float*)d_in[5];
    const float* b2   = (const float*)d_in[6];
    float* out = (float*)d_out;

    // ws layout (~14.0 MB):
    //   [0        , 7206912 )  pairs/csr slabs (NB * SLAB u32, 16B aligned)
    //   [7208960  , +3.2M   )  Yu   (bf16x16 rows, packed, 16B aligned)
    //   [10408960 , +3.2M   )  H1u  (bf16x16 rows, packed, 16B aligned)
    //   [13608960 , +1.6K   )  cursor   (NB ints, zero-based counts)
    //   [13613056 , +402K   )  node_off (NB*257 ints)
    char* base = (char*)d_ws;
    unsigned* pairs    = (unsigned*)(base);
    unsigned* Yu       = (unsigned*)(base + 7208960);
    unsigned* H1u      = (unsigned*)(base + 10408960);
    int*      cursor   = (int*)(base + 13608960);
    int*      node_off = (int*)(base + 13613056);

    // cursor zeroing (1.6 KB)
    hipMemsetAsync(cursor, 0, NB * sizeof(int), stream);

    // K1: fused sortscatter (391 blocks) + mm1 (1563 blocks)
    k_fused1   <<<SBLOCKS + MMBLOCKS, 256, 0, stream>>>(feat, W1, src, dst,
                                                        cursor, pairs, Yu);
    // K2: merged node sort + layer-1 aggregation (LDS-resident indices)
    k_sortagg1 <<<NB, 1024, 0, stream>>>(cursor, pairs, (const uint2*)Yu, b1,
                                         (uint2*)H1u, node_off);
    // K3: layer-2 aggregation (uint4 index loads) + fused mm2
    k_agg2     <<<(N_NODES + 63) / 64, 256, 0, stream>>>(node_off, pairs,
                                                         (const uint2*)H1u, W2, b2, out);
}

// Round 19
// 75.789 us; speedup vs baseline: 1.3094x; 1.0665x over previous
//
#include <hip/hip_runtime.h>
#include <hip/hip_bf16.h>

#define N_NODES 100000
#define N_EDGES 1600000
#define D_IN    128
#define D_HID   16
#define D_OUT   32

#define BSHIFT 8
#define BNODES 256                 // nodes per bucket
#define NB 391                     // ceil(100000/256)
#define NBPAD 512
#define SCHUNK 4096                // edges per sort block
#define SBLOCKS 391                // ceil(1600000/4096)
#define MMBLOCKS 1563              // mm1: 1 node/thread-quad (proven)
#define SLAB 4608                  // slab slots per bucket (mean 4096, +8 sigma)
#define NOSTRIDE 257               // node_off stride per bucket (256 + sentinel)

// shared-memory union layout for the fused kernel (bytes)
#define SS_HIST   0                // int[512]
#define SS_LBASE  2048             // int[512]
#define SS_GBASE  4096             // int[391] (pad to 1600)
#define SS_TSCAN  5696             // int[256]
#define SS_SORTED 6720             // unsigned[4096]
#define SS_BID    23104            // ushort[4096]
#define SS_BYTES  31296            // 31.3 KB -> 5 blocks/CU

// bf16x2 helpers -------------------------------------------------------------
__device__ inline float bf_lo(unsigned dw) { return __uint_as_float(dw << 16); }
__device__ inline float bf_hi(unsigned dw) { return __uint_as_float(dw & 0xffff0000u); }
__device__ inline unsigned bf_pack(float f0, float f1) {
    union { __hip_bfloat16 h[2]; unsigned u; } pu;
    pu.h[0] = __float2bfloat16(f0);
    pu.h[1] = __float2bfloat16(f1);
    return pu.u;
}
__device__ inline void acc4(float* a, uint2 w) {
    a[0] += bf_lo(w.x); a[1] += bf_hi(w.x);
    a[2] += bf_lo(w.y); a[3] += bf_hi(w.y);
}

// ---------------------------------------------------------------------------
// K1 (fused, proven r16-r18): blocks [0, SBLOCKS) = bucket-grouping counting
// sort (zero-based slab cursors); blocks [SBLOCKS, ..) = mm1 at 1 node/
// thread-quad. Disjoint inputs, complementary bottlenecks, co-resident.
// ---------------------------------------------------------------------------
__global__ __launch_bounds__(256) void k_fused1(const float* __restrict__ feat,
                                                const float* __restrict__ W1,
                                                const int* __restrict__ src,
                                                const int* __restrict__ dst,
                                                int* __restrict__ cursor,
                                                unsigned* __restrict__ pairs,
                                                unsigned* __restrict__ Yu) {
    __shared__ __align__(16) char smem[SS_BYTES];
    int tid = threadIdx.x, blk = blockIdx.x;

    if (blk < SBLOCKS) {
        // ---------------- sortscatter path ----------------
        int* hist    = (int*)(smem + SS_HIST);
        int* lbase   = (int*)(smem + SS_LBASE);
        int* gbase   = (int*)(smem + SS_GBASE);
        int* tscan   = (int*)(smem + SS_TSCAN);
        unsigned* sorted = (unsigned*)(smem + SS_SORTED);
        unsigned short* bId = (unsigned short*)(smem + SS_BID);

        int base = blk * SCHUNK;
        int nval = N_EDGES - base;
        if (nval > SCHUNK) nval = SCHUNK;

        for (int i = tid; i < NBPAD; i += 256) hist[i] = 0;
        __syncthreads();

        int varr[16], barr[16];
#pragma unroll
        for (int k = 0; k < 16; ++k) {
            int e = base + k * 256 + tid;
            if (e < N_EDGES) {
                int s = src[e], d = dst[e];
                varr[k] = (s << BSHIFT) | (d & (BNODES - 1));
                int b = d >> BSHIFT;
                barr[k] = b;
                atomicAdd(&hist[b], 1);
            } else {
                barr[k] = -1;
            }
        }
        __syncthreads();

        int i0 = tid * 2;
        int h0 = hist[i0], h1 = hist[i0 + 1];
        int lsum = h0 + h1;
        tscan[tid] = lsum;
        __syncthreads();
#pragma unroll
        for (int off = 1; off < 256; off <<= 1) {
            int x = (tid >= off) ? tscan[tid - off] : 0;
            __syncthreads();
            tscan[tid] += x;
            __syncthreads();
        }
        int excl = tscan[tid] - lsum;
        lbase[i0 + 0] = excl;
        lbase[i0 + 1] = excl + h0;
        __syncthreads();

        for (int i = tid; i < NB; i += 256) {
            int c = hist[i];
            if (c > 0) gbase[i] = i * SLAB + atomicAdd(&cursor[i], c);
        }
        __syncthreads();
        for (int i = tid; i < NBPAD; i += 256) hist[i] = 0;   // -> placement cnt
        __syncthreads();

#pragma unroll
        for (int k = 0; k < 16; ++k) {
            int b = barr[k];
            if (b >= 0) {
                int r = atomicAdd(&hist[b], 1);
                int p = lbase[b] + r;
                sorted[p] = (unsigned)varr[k];
                bId[p] = (unsigned short)b;
            }
        }
        __syncthreads();

        for (int i = tid; i < nval; i += 256) {
            int b = bId[i];
            pairs[gbase[b] + (i - lbase[b])] = sorted[i];
        }
    } else {
        // ---------------- mm1 path (1 node/thread-quad) ----------------
        float* sW = (float*)smem;           // first 8 KB of the union
        for (int i = tid; i < D_IN * D_HID; i += 256) sW[i] = W1[i];
        __syncthreads();

        int gid = (blk - SBLOCKS) * 256 + tid;
        int n = gid >> 2;          // node
        int jq = gid & 3;          // output quad
        if (n >= N_NODES) return;

        const float4* f4 = (const float4*)(feat + (size_t)n * D_IN);
        const float4* sW4 = (const float4*)sW;

        float4 acc = make_float4(0.f, 0.f, 0.f, 0.f);
#pragma unroll 8
        for (int kq = 0; kq < 32; ++kq) {
            float4 f = f4[kq];
            int k0 = kq * 4;
            float4 w0 = sW4[(k0 + 0) * 4 + jq];
            float4 w1 = sW4[(k0 + 1) * 4 + jq];
            float4 w2 = sW4[(k0 + 2) * 4 + jq];
            float4 w3 = sW4[(k0 + 3) * 4 + jq];
            acc.x += f.x * w0.x + f.y * w1.x + f.z * w2.x + f.w * w3.x;
            acc.y += f.x * w0.y + f.y * w1.y + f.z * w2.y + f.w * w3.y;
            acc.z += f.x * w0.z + f.y * w1.z + f.z * w2.z + f.w * w3.z;
            acc.w += f.x * w0.w + f.y * w1.w + f.z * w2.w + f.w * w3.w;
        }
        uint2 o;
        o.x = bf_pack(acc.x, acc.y);
        o.y = bf_pack(acc.z, acc.w);
        ((uint2*)(Yu + (size_t)n * 8))[jq] = o;
    }
}

// ---------------------------------------------------------------------------
// K2 (merged): per-bucket node sort + layer-1 aggregation, 1024 threads.
// Placement writes LDS only; the global csr writeback is a separate
// COALESCED copy-out from sbuf (replaces r18's scattered 4B writes).
// Phase 2 gathers with LDS-resident indices (zero index VMEM).
// ---------------------------------------------------------------------------
__global__ __launch_bounds__(1024) void k_sortagg1(const int* __restrict__ cursor,
                                                   unsigned* __restrict__ pairs,
                                                   const uint2* __restrict__ Yu2,
                                                   const float* __restrict__ bias1,
                                                   uint2* __restrict__ H1u2,
                                                   int* __restrict__ node_off) {
    __shared__ unsigned buf[SLAB];      // 18 KB
    __shared__ unsigned sbuf[SLAB];     // 18 KB (node-sorted src ids)
    __shared__ int hist[BNODES];        // 1 KB
    __shared__ int lbase[BNODES];
    __shared__ int cur[BNODES];
    __shared__ int t[BNODES];
    __shared__ float sB[D_HID];

    int tid = threadIdx.x, b = blockIdx.x;
    int beg = b * SLAB;
    int cnt = cursor[b];

    if (tid < BNODES) hist[tid] = 0;
    if (tid < D_HID) sB[tid] = bias1[tid];
    __syncthreads();

    for (int i = tid; i < cnt; i += 1024) {
        unsigned p = pairs[beg + i];
        buf[i] = p;
        atomicAdd(&hist[p & (BNODES - 1)], 1);
    }
    __syncthreads();

    // exclusive scan over 256 keys (threads 0..255 active)
    if (tid < BNODES) t[tid] = hist[tid];
    __syncthreads();
#pragma unroll
    for (int off = 1; off < BNODES; off <<= 1) {
        int x = 0;
        if (tid < BNODES && tid >= off) x = t[tid - off];
        __syncthreads();
        if (tid < BNODES) t[tid] += x;
        __syncthreads();
    }
    if (tid < BNODES) {
        int excl = t[tid] - hist[tid];
        lbase[tid] = excl;
        cur[tid] = excl;
        node_off[b * NOSTRIDE + tid] = beg + excl;
        if (tid == 0) node_off[b * NOSTRIDE + BNODES] = beg + cnt;
    }
    __syncthreads();

    // place: sorted src ids into LDS sbuf only (no scattered global writes)
    for (int i = tid; i < cnt; i += 1024) {
        unsigned p = buf[i];
        int pos = atomicAdd(&cur[p & (BNODES - 1)], 1);
        sbuf[pos] = p >> BSHIFT;
    }
    __syncthreads();

    // coalesced csr writeback for agg2
    for (int i = tid; i < cnt; i += 1024)
        pairs[beg + i] = sbuf[i];

    // phase 2: aggregate; indices from LDS (LGKM pipe, overlaps gathers)
    int g = tid >> 2, c = tid & 3;
    int n = b * BNODES + g;
    if (n >= N_NODES) return;
    int i = lbase[g];
    int e = cur[g];                    // cur = lbase + count after placement

    float a[4] = {0.f, 0.f, 0.f, 0.f}, bb[4] = {0.f, 0.f, 0.f, 0.f};
    for (; i + 7 < e; i += 8) {
        unsigned s0 = sbuf[i],     s1 = sbuf[i + 1], s2 = sbuf[i + 2], s3 = sbuf[i + 3];
        unsigned s4 = sbuf[i + 4], s5 = sbuf[i + 5], s6 = sbuf[i + 6], s7 = sbuf[i + 7];
        uint2 w0 = Yu2[(size_t)s0 * 4 + c];
        uint2 w1 = Yu2[(size_t)s1 * 4 + c];
        uint2 w2 = Yu2[(size_t)s2 * 4 + c];
        uint2 w3 = Yu2[(size_t)s3 * 4 + c];
        uint2 w4 = Yu2[(size_t)s4 * 4 + c];
        uint2 w5 = Yu2[(size_t)s5 * 4 + c];
        uint2 w6 = Yu2[(size_t)s6 * 4 + c];
        uint2 w7 = Yu2[(size_t)s7 * 4 + c];
        acc4(a, w0); acc4(bb, w1); acc4(a, w2); acc4(bb, w3);
        acc4(a, w4); acc4(bb, w5); acc4(a, w6); acc4(bb, w7);
    }
    for (; i + 3 < e; i += 4) {        // 4-deep mid-tail
        unsigned s0 = sbuf[i], s1 = sbuf[i + 1], s2 = sbuf[i + 2], s3 = sbuf[i + 3];
        uint2 w0 = Yu2[(size_t)s0 * 4 + c];
        uint2 w1 = Yu2[(size_t)s1 * 4 + c];
        uint2 w2 = Yu2[(size_t)s2 * 4 + c];
        uint2 w3 = Yu2[(size_t)s3 * 4 + c];
        acc4(a, w0); acc4(bb, w1); acc4(a, w2); acc4(bb, w3);
    }
    for (; i < e; ++i) {
        uint2 w = Yu2[(size_t)sbuf[i] * 4 + c];
        acc4(a, w);
    }
    float f0 = a[0] + bb[0] + sB[c * 4 + 0];
    float f1 = a[1] + bb[1] + sB[c * 4 + 1];
    float f2 = a[2] + bb[2] + sB[c * 4 + 2];
    float f3 = a[3] + bb[3] + sB[c * 4 + 3];
    uint2 o;
    o.x = bf_pack(fmaxf(f0, 0.f), fmaxf(f1, 0.f));
    o.y = bf_pack(fmaxf(f2, 0.f), fmaxf(f3, 0.f));
    H1u2[(size_t)n * 4 + c] = o;
}

// ---------------------------------------------------------------------------
// K3: layer-2 aggregation per bucket (1024 threads) + fused mm2 epilogue.
// Stages the bucket's csr slab into LDS with coalesced loads, node bounds
// from node_off into LDS, then gathers with LDS-resident indices (zero index
// VMEM — same mechanism that won in r18's sortagg1). LDS ~39 KB -> 2 blk/CU
// at 1024 threads (32 waves/CU, the residency cap).
// ---------------------------------------------------------------------------
__global__ __launch_bounds__(1024) void k_agg2(const int* __restrict__ node_off,
                                               const unsigned* __restrict__ csr,
                                               const uint2* __restrict__ H1u2,
                                               const float* __restrict__ W2,
                                               const float* __restrict__ b2,
                                               float* __restrict__ out) {
    __shared__ unsigned sidx[SLAB];          // 18 KB
    __shared__ int nb[BNODES + 1];           // node bounds (global indices)
    __shared__ float sacc[BNODES][D_HID + 1];// 17.4 KB
    __shared__ float sW2[D_HID * D_OUT];     // 2 KB
    __shared__ float sb2[D_OUT];

    int tid = threadIdx.x, b = blockIdx.x;
    int beg = b * SLAB;
    for (int i = tid; i < D_HID * D_OUT; i += 1024) sW2[i] = W2[i];
    if (tid < D_OUT) sb2[tid] = b2[tid];
    if (tid <= BNODES) nb[tid] = node_off[b * NOSTRIDE + tid];
    __syncthreads();

    int cnt = nb[BNODES] - beg;
    for (int i = tid; i < cnt; i += 1024) sidx[i] = csr[beg + i];
    __syncthreads();

    int g = tid >> 2, c = tid & 3;
    int n = b * BNODES + g;
    float a[4] = {0.f, 0.f, 0.f, 0.f}, bb[4] = {0.f, 0.f, 0.f, 0.f};
    if (n < N_NODES) {
        int i = nb[g] - beg, e = nb[g + 1] - beg;
        for (; i + 7 < e; i += 8) {
            unsigned s0 = sidx[i],     s1 = sidx[i + 1], s2 = sidx[i + 2], s3 = sidx[i + 3];
            unsigned s4 = sidx[i + 4], s5 = sidx[i + 5], s6 = sidx[i + 6], s7 = sidx[i + 7];
            uint2 w0 = H1u2[(size_t)s0 * 4 + c];
            uint2 w1 = H1u2[(size_t)s1 * 4 + c];
            uint2 w2 = H1u2[(size_t)s2 * 4 + c];
            uint2 w3 = H1u2[(size_t)s3 * 4 + c];
            uint2 w4 = H1u2[(size_t)s4 * 4 + c];
            uint2 w5 = H1u2[(size_t)s5 * 4 + c];
            uint2 w6 = H1u2[(size_t)s6 * 4 + c];
            uint2 w7 = H1u2[(size_t)s7 * 4 + c];
            acc4(a, w0); acc4(bb, w1); acc4(a, w2); acc4(bb, w3);
            acc4(a, w4); acc4(bb, w5); acc4(a, w6); acc4(bb, w7);
        }
        for (; i + 3 < e; i += 4) {    // 4-deep mid-tail
            unsigned s0 = sidx[i], s1 = sidx[i + 1], s2 = sidx[i + 2], s3 = sidx[i + 3];
            uint2 w0 = H1u2[(size_t)s0 * 4 + c];
            uint2 w1 = H1u2[(size_t)s1 * 4 + c];
            uint2 w2 = H1u2[(size_t)s2 * 4 + c];
            uint2 w3 = H1u2[(size_t)s3 * 4 + c];
            acc4(a, w0); acc4(bb, w1); acc4(a, w2); acc4(bb, w3);
        }
        for (; i < e; ++i) {
            uint2 w = H1u2[(size_t)sidx[i] * 4 + c];
            acc4(a, w);
        }
    }
    sacc[g][c * 4 + 0] = a[0] + bb[0];
    sacc[g][c * 4 + 1] = a[1] + bb[1];
    sacc[g][c * 4 + 2] = a[2] + bb[2];
    sacc[g][c * 4 + 3] = a[3] + bb[3];
    __syncthreads();

    // mm2: 256 nodes x 32 outputs = 8192 -> 8 per thread
    for (int t2 = tid; t2 < BNODES * D_OUT; t2 += 1024) {
        int gg = t2 >> 5, o = t2 & 31;
        int node = b * BNODES + gg;
        if (node < N_NODES) {
            float acc = sb2[o];
#pragma unroll
            for (int j = 0; j < D_HID; ++j)
                acc = fmaf(sacc[gg][j], sW2[j * D_OUT + o], acc);
            out[(size_t)node * D_OUT + o] = acc;
        }
    }
}

// ---------------------------------------------------------------------------
extern "C" void kernel_launch(void* const* d_in, const int* in_sizes, int n_in,
                              void* d_out, int out_size, void* d_ws, size_t ws_size,
                              hipStream_t stream) {
    const float* feat = (const float*)d_in[0];
    const int*   src  = (const int*)d_in[1];
    const int*   dst  = (const int*)d_in[2];
    const float* W1   = (const float*)d_in[3];
    const float* b1   = (const float*)d_in[4];
    const float* W2   = (const float*)d_in[5];
    const float* b2   = (const float*)d_in[6];
    float* out = (float*)d_out;

    // ws layout (~14.0 MB):
    //   [0        , 7206912 )  pairs/csr slabs (NB * SLAB u32, 16B aligned)
    //   [7208960  , +3.2M   )  Yu   (bf16x16 rows, packed, 16B aligned)
    //   [10408960 , +3.2M   )  H1u  (bf16x16 rows, packed, 16B aligned)
    //   [13608960 , +1.6K   )  cursor   (NB ints, zero-based counts)
    //   [13613056 , +402K   )  node_off (NB*257 ints)
    char* base = (char*)d_ws;
    unsigned* pairs    = (unsigned*)(base);
    unsigned* Yu       = (unsigned*)(base + 7208960);
    unsigned* H1u      = (unsigned*)(base + 10408960);
    int*      cursor   = (int*)(base + 13608960);
    int*      node_off = (int*)(base + 13613056);

    // cursor zeroing (1.6 KB)
    hipMemsetAsync(cursor, 0, NB * sizeof(int), stream);

    // K1: fused sortscatter (391 blocks) + mm1 (1563 blocks)
    k_fused1   <<<SBLOCKS + MMBLOCKS, 256, 0, stream>>>(feat, W1, src, dst,
                                                        cursor, pairs, Yu);
    // K2: merged node sort + layer-1 aggregation (LDS indices, coalesced csr)
    k_sortagg1 <<<NB, 1024, 0, stream>>>(cursor, pairs, (const uint2*)Yu, b1,
                                         (uint2*)H1u, node_off);
    // K3: layer-2 aggregation per bucket (LDS-staged indices) + fused mm2
    k_agg2     <<<NB, 1024, 0, stream>>>(node_off, pairs, (const uint2*)H1u,
                                         W2, b2, out);
}

// Round 20
// 74.901 us; speedup vs baseline: 1.3250x; 1.0119x over previous
//
#include <hip/hip_runtime.h>
#include <hip/hip_bf16.h>

#define N_NODES 100000
#define N_EDGES 1600000
#define D_IN    128
#define D_HID   16
#define D_OUT   32

#define BSHIFT 8
#define BNODES 256                 // nodes per bucket
#define NB 391                     // ceil(100000/256)
#define NBPAD 512
#define SCHUNK 4096                // edges per sort block
#define SBLOCKS 391                // ceil(1600000/4096)
#define MMBLOCKS 1563              // mm1: 1 node/thread-quad (proven)
#define SLAB 4608                  // slab slots per bucket (mean 4096, +8 sigma)
#define NOSTRIDE 257               // node_off stride per bucket (256 + sentinel)

// shared-memory union layout for the fused kernel (bytes)
#define SS_HIST   0                // int[512]
#define SS_LBASE  2048             // int[512]
#define SS_GBASE  4096             // int[391] (pad to 1600)
#define SS_TSCAN  5696             // int[256]
#define SS_SORTED 6720             // unsigned[4096]
#define SS_BID    23104            // ushort[4096]
#define SS_BYTES  31296            // 31.3 KB -> 5 blocks/CU

// bf16x2 helpers -------------------------------------------------------------
__device__ inline float bf_lo(unsigned dw) { return __uint_as_float(dw << 16); }
__device__ inline float bf_hi(unsigned dw) { return __uint_as_float(dw & 0xffff0000u); }
__device__ inline unsigned bf_pack(float f0, float f1) {
    union { __hip_bfloat16 h[2]; unsigned u; } pu;
    pu.h[0] = __float2bfloat16(f0);
    pu.h[1] = __float2bfloat16(f1);
    return pu.u;
}
__device__ inline void acc8(float* a, uint4 w) {
    a[0] += bf_lo(w.x); a[1] += bf_hi(w.x);
    a[2] += bf_lo(w.y); a[3] += bf_hi(w.y);
    a[4] += bf_lo(w.z); a[5] += bf_hi(w.z);
    a[6] += bf_lo(w.w); a[7] += bf_hi(w.w);
}

// ---------------------------------------------------------------------------
// K1 (fused, proven r16-r19): blocks [0, SBLOCKS) = bucket-grouping counting
// sort (zero-based slab cursors); blocks [SBLOCKS, ..) = mm1 at 1 node/
// thread-quad. Disjoint inputs, complementary bottlenecks, co-resident.
// ---------------------------------------------------------------------------
__global__ __launch_bounds__(256) void k_fused1(const float* __restrict__ feat,
                                                const float* __restrict__ W1,
                                                const int* __restrict__ src,
                                                const int* __restrict__ dst,
                                                int* __restrict__ cursor,
                                                unsigned* __restrict__ pairs,
                                                unsigned* __restrict__ Yu) {
    __shared__ __align__(16) char smem[SS_BYTES];
    int tid = threadIdx.x, blk = blockIdx.x;

    if (blk < SBLOCKS) {
        // ---------------- sortscatter path ----------------
        int* hist    = (int*)(smem + SS_HIST);
        int* lbase   = (int*)(smem + SS_LBASE);
        int* gbase   = (int*)(smem + SS_GBASE);
        int* tscan   = (int*)(smem + SS_TSCAN);
        unsigned* sorted = (unsigned*)(smem + SS_SORTED);
        unsigned short* bId = (unsigned short*)(smem + SS_BID);

        int base = blk * SCHUNK;
        int nval = N_EDGES - base;
        if (nval > SCHUNK) nval = SCHUNK;

        for (int i = tid; i < NBPAD; i += 256) hist[i] = 0;
        __syncthreads();

        int varr[16], barr[16];
#pragma unroll
        for (int k = 0; k < 16; ++k) {
            int e = base + k * 256 + tid;
            if (e < N_EDGES) {
                int s = src[e], d = dst[e];
                varr[k] = (s << BSHIFT) | (d & (BNODES - 1));
                int b = d >> BSHIFT;
                barr[k] = b;
                atomicAdd(&hist[b], 1);
            } else {
                barr[k] = -1;
            }
        }
        __syncthreads();

        int i0 = tid * 2;
        int h0 = hist[i0], h1 = hist[i0 + 1];
        int lsum = h0 + h1;
        tscan[tid] = lsum;
        __syncthreads();
#pragma unroll
        for (int off = 1; off < 256; off <<= 1) {
            int x = (tid >= off) ? tscan[tid - off] : 0;
            __syncthreads();
            tscan[tid] += x;
            __syncthreads();
        }
        int excl = tscan[tid] - lsum;
        lbase[i0 + 0] = excl;
        lbase[i0 + 1] = excl + h0;
        __syncthreads();

        for (int i = tid; i < NB; i += 256) {
            int c = hist[i];
            if (c > 0) gbase[i] = i * SLAB + atomicAdd(&cursor[i], c);
        }
        __syncthreads();
        for (int i = tid; i < NBPAD; i += 256) hist[i] = 0;   // -> placement cnt
        __syncthreads();

#pragma unroll
        for (int k = 0; k < 16; ++k) {
            int b = barr[k];
            if (b >= 0) {
                int r = atomicAdd(&hist[b], 1);
                int p = lbase[b] + r;
                sorted[p] = (unsigned)varr[k];
                bId[p] = (unsigned short)b;
            }
        }
        __syncthreads();

        for (int i = tid; i < nval; i += 256) {
            int b = bId[i];
            pairs[gbase[b] + (i - lbase[b])] = sorted[i];
        }
    } else {
        // ---------------- mm1 path (1 node/thread-quad) ----------------
        float* sW = (float*)smem;           // first 8 KB of the union
        for (int i = tid; i < D_IN * D_HID; i += 256) sW[i] = W1[i];
        __syncthreads();

        int gid = (blk - SBLOCKS) * 256 + tid;
        int n = gid >> 2;          // node
        int jq = gid & 3;          // output quad
        if (n >= N_NODES) return;

        const float4* f4 = (const float4*)(feat + (size_t)n * D_IN);
        const float4* sW4 = (const float4*)sW;

        float4 acc = make_float4(0.f, 0.f, 0.f, 0.f);
#pragma unroll 8
        for (int kq = 0; kq < 32; ++kq) {
            float4 f = f4[kq];
            int k0 = kq * 4;
            float4 w0 = sW4[(k0 + 0) * 4 + jq];
            float4 w1 = sW4[(k0 + 1) * 4 + jq];
            float4 w2 = sW4[(k0 + 2) * 4 + jq];
            float4 w3 = sW4[(k0 + 3) * 4 + jq];
            acc.x += f.x * w0.x + f.y * w1.x + f.z * w2.x + f.w * w3.x;
            acc.y += f.x * w0.y + f.y * w1.y + f.z * w2.y + f.w * w3.y;
            acc.z += f.x * w0.z + f.y * w1.z + f.z * w2.z + f.w * w3.z;
            acc.w += f.x * w0.w + f.y * w1.w + f.z * w2.w + f.w * w3.w;
        }
        uint2 o;
        o.x = bf_pack(acc.x, acc.y);
        o.y = bf_pack(acc.z, acc.w);
        ((uint2*)(Yu + (size_t)n * 8))[jq] = o;
    }
}

// ---------------------------------------------------------------------------
// K2 (merged): per-bucket node sort + layer-1 aggregation, 1024 threads.
// Phase 2 uses parity-split lanes: lane (h,p) gathers the h-th uint4 half-row
// of edges with parity p -> 4 gather instrs per 8 edges per lane (2x fewer
// VMEM instrs than 4-lane uint2), indices from LDS, all threads busy.
// Parity lanes merged at the end with one __shfl_xor(.,2) pass.
// ---------------------------------------------------------------------------
__global__ __launch_bounds__(1024) void k_sortagg1(const int* __restrict__ cursor,
                                                   unsigned* __restrict__ pairs,
                                                   const uint4* __restrict__ Yu4,
                                                   const float* __restrict__ bias1,
                                                   uint4* __restrict__ H1u4,
                                                   int* __restrict__ node_off) {
    __shared__ unsigned buf[SLAB];      // 18 KB
    __shared__ unsigned sbuf[SLAB];     // 18 KB (node-sorted src ids)
    __shared__ int hist[BNODES];        // 1 KB
    __shared__ int lbase[BNODES];
    __shared__ int cur[BNODES];
    __shared__ int t[BNODES];
    __shared__ float sB[D_HID];

    int tid = threadIdx.x, b = blockIdx.x;
    int beg = b * SLAB;
    int cnt = cursor[b];

    if (tid < BNODES) hist[tid] = 0;
    if (tid < D_HID) sB[tid] = bias1[tid];
    __syncthreads();

    for (int i = tid; i < cnt; i += 1024) {
        unsigned p = pairs[beg + i];
        buf[i] = p;
        atomicAdd(&hist[p & (BNODES - 1)], 1);
    }
    __syncthreads();

    // exclusive scan over 256 keys (threads 0..255 active)
    if (tid < BNODES) t[tid] = hist[tid];
    __syncthreads();
#pragma unroll
    for (int off = 1; off < BNODES; off <<= 1) {
        int x = 0;
        if (tid < BNODES && tid >= off) x = t[tid - off];
        __syncthreads();
        if (tid < BNODES) t[tid] += x;
        __syncthreads();
    }
    if (tid < BNODES) {
        int excl = t[tid] - hist[tid];
        lbase[tid] = excl;
        cur[tid] = excl;
        node_off[b * NOSTRIDE + tid] = beg + excl;
        if (tid == 0) node_off[b * NOSTRIDE + BNODES] = beg + cnt;
    }
    __syncthreads();

    // place: sorted src ids into LDS sbuf only
    for (int i = tid; i < cnt; i += 1024) {
        unsigned p = buf[i];
        int pos = atomicAdd(&cur[p & (BNODES - 1)], 1);
        sbuf[pos] = p >> BSHIFT;
    }
    __syncthreads();

    // coalesced csr writeback for agg2
    for (int i = tid; i < cnt; i += 1024)
        pairs[beg + i] = sbuf[i];

    // phase 2: parity-split gather (indices from LDS)
    int g = tid >> 2, q = tid & 3;
    int h = q & 1, p = q >> 1;
    int n = b * BNODES + g;
    if (n >= N_NODES) return;
    int i = lbase[g];
    int e = cur[g];

    float a[8] = {0,0,0,0,0,0,0,0}, bb[8] = {0,0,0,0,0,0,0,0};
    for (; i + 7 < e; i += 8) {
        unsigned s0 = sbuf[i + p];
        unsigned s1 = sbuf[i + p + 2];
        unsigned s2 = sbuf[i + p + 4];
        unsigned s3 = sbuf[i + p + 6];
        uint4 w0 = Yu4[(size_t)s0 * 2 + h];
        uint4 w1 = Yu4[(size_t)s1 * 2 + h];
        uint4 w2 = Yu4[(size_t)s2 * 2 + h];
        uint4 w3 = Yu4[(size_t)s3 * 2 + h];
        acc8(a, w0); acc8(bb, w1); acc8(a, w2); acc8(bb, w3);
    }
    for (; i + 1 < e; i += 2) {          // pair tail
        unsigned s0 = sbuf[i + p];
        uint4 w = Yu4[(size_t)s0 * 2 + h];
        acc8(a, w);
    }
    if (i < e && p == 0) {               // odd final edge
        uint4 w = Yu4[(size_t)sbuf[i] * 2 + h];
        acc8(a, w);
    }
#pragma unroll
    for (int j = 0; j < 8; ++j) {
        float v = a[j] + bb[j];
        v += __shfl_xor(v, 2);           // merge parity lanes
        a[j] = v;
    }
    if (p == 0) {
        float f[8];
#pragma unroll
        for (int j = 0; j < 8; ++j)
            f[j] = fmaxf(a[j] + sB[h * 8 + j], 0.f);
        uint4 o;
        o.x = bf_pack(f[0], f[1]);
        o.y = bf_pack(f[2], f[3]);
        o.z = bf_pack(f[4], f[5]);
        o.w = bf_pack(f[6], f[7]);
        H1u4[(size_t)n * 2 + h] = o;
    }
}

// ---------------------------------------------------------------------------
// K3: layer-2 aggregation per bucket (1024 threads) + fused mm2 epilogue.
// LDS-staged indices + parity-split uint4 gathers (same mechanism as K2).
// ---------------------------------------------------------------------------
__global__ __launch_bounds__(1024) void k_agg2(const int* __restrict__ node_off,
                                               const unsigned* __restrict__ csr,
                                               const uint4* __restrict__ H1u4,
                                               const float* __restrict__ W2,
                                               const float* __restrict__ b2,
                                               float* __restrict__ out) {
    __shared__ unsigned sidx[SLAB];          // 18 KB
    __shared__ int nb[BNODES + 1];
    __shared__ float sacc[BNODES][D_HID + 1];// 17.4 KB
    __shared__ float sW2[D_HID * D_OUT];     // 2 KB
    __shared__ float sb2[D_OUT];

    int tid = threadIdx.x, b = blockIdx.x;
    int beg = b * SLAB;
    for (int i = tid; i < D_HID * D_OUT; i += 1024) sW2[i] = W2[i];
    if (tid < D_OUT) sb2[tid] = b2[tid];
    if (tid <= BNODES) nb[tid] = node_off[b * NOSTRIDE + tid];
    __syncthreads();

    int cnt = nb[BNODES] - beg;
    for (int i = tid; i < cnt; i += 1024) sidx[i] = csr[beg + i];
    __syncthreads();

    int g = tid >> 2, q = tid & 3;
    int h = q & 1, p = q >> 1;
    int n = b * BNODES + g;
    float a[8] = {0,0,0,0,0,0,0,0}, bb[8] = {0,0,0,0,0,0,0,0};
    if (n < N_NODES) {
        int i = nb[g] - beg, e = nb[g + 1] - beg;
        for (; i + 7 < e; i += 8) {
            unsigned s0 = sidx[i + p];
            unsigned s1 = sidx[i + p + 2];
            unsigned s2 = sidx[i + p + 4];
            unsigned s3 = sidx[i + p + 6];
            uint4 w0 = H1u4[(size_t)s0 * 2 + h];
            uint4 w1 = H1u4[(size_t)s1 * 2 + h];
            uint4 w2 = H1u4[(size_t)s2 * 2 + h];
            uint4 w3 = H1u4[(size_t)s3 * 2 + h];
            acc8(a, w0); acc8(bb, w1); acc8(a, w2); acc8(bb, w3);
        }
        for (; i + 1 < e; i += 2) {
            unsigned s0 = sidx[i + p];
            uint4 w = H1u4[(size_t)s0 * 2 + h];
            acc8(a, w);
        }
        if (i < e && p == 0) {
            uint4 w = H1u4[(size_t)sidx[i] * 2 + h];
            acc8(a, w);
        }
    }
#pragma unroll
    for (int j = 0; j < 8; ++j) {
        float v = a[j] + bb[j];
        v += __shfl_xor(v, 2);
        a[j] = v;
    }
    if (p == 0) {
#pragma unroll
        for (int j = 0; j < 8; ++j)
            sacc[g][h * 8 + j] = a[j];
    }
    __syncthreads();

    // mm2: 256 nodes x 32 outputs = 8192 -> 8 per thread
    for (int t2 = tid; t2 < BNODES * D_OUT; t2 += 1024) {
        int gg = t2 >> 5, o = t2 & 31;
        int node = b * BNODES + gg;
        if (node < N_NODES) {
            float acc = sb2[o];
#pragma unroll
            for (int j = 0; j < D_HID; ++j)
                acc = fmaf(sacc[gg][j], sW2[j * D_OUT + o], acc);
            out[(size_t)node * D_OUT + o] = acc;
        }
    }
}

// ---------------------------------------------------------------------------
extern "C" void kernel_launch(void* const* d_in, const int* in_sizes, int n_in,
                              void* d_out, int out_size, void* d_ws, size_t ws_size,
                              hipStream_t stream) {
    const float* feat = (const float*)d_in[0];
    const int*   src  = (const int*)d_in[1];
    const int*   dst  = (const int*)d_in[2];
    const float* W1   = (const float*)d_in[3];
    const float* b1   = (const float*)d_in[4];
    const float* W2   = (const float*)d_in[5];
    const float* b2   = (const float*)d_in[6];
    float* out = (float*)d_out;

    // ws layout (~14.0 MB):
    //   [0        , 7206912 )  pairs/csr slabs (NB * SLAB u32, 16B aligned)
    //   [7208960  , +3.2M   )  Yu   (bf16x16 rows, packed, 16B aligned)
    //   [10408960 , +3.2M   )  H1u  (bf16x16 rows, packed, 16B aligned)
    //   [13608960 , +1.6K   )  cursor   (NB ints, zero-based counts)
    //   [13613056 , +402K   )  node_off (NB*257 ints)
    char* base = (char*)d_ws;
    unsigned* pairs    = (unsigned*)(base);
    unsigned* Yu       = (unsigned*)(base + 7208960);
    unsigned* H1u      = (unsigned*)(base + 10408960);
    int*      cursor   = (int*)(base + 13608960);
    int*      node_off = (int*)(base + 13613056);

    // cursor zeroing (1.6 KB)
    hipMemsetAsync(cursor, 0, NB * sizeof(int), stream);

    // K1: fused sortscatter (391 blocks) + mm1 (1563 blocks)
    k_fused1   <<<SBLOCKS + MMBLOCKS, 256, 0, stream>>>(feat, W1, src, dst,
                                                        cursor, pairs, Yu);
    // K2: merged node sort + layer-1 aggregation (parity-split uint4 gathers)
    k_sortagg1 <<<NB, 1024, 0, stream>>>(cursor, pairs, (const uint4*)Yu, b1,
                                         (uint4*)H1u, node_off);
    // K3: layer-2 aggregation (parity-split uint4 gathers) + fused mm2
    k_agg2     <<<NB, 1024, 0, stream>>>(node_off, pairs, (const uint4*)H1u,
                                         W2, b2, out);
}